// Round 8
// baseline (342.794 us; speedup 1.0000x reference)
//
#include <hip/hip_runtime.h>
#include <hip/hip_fp16.h>

#define N0 50000
#define N1 100000
#define N2 25000
#define E00 200000
#define E11 200000
#define E10 100000
#define E21 50000
#define EE  550000   // E00+E10+E11+E21 (concatenated edge space)
#define ND  300000   // 50000(u00)+50000(b10)+100000(u11)+100000(b21) dst slots
#define NB  293      // ceil(ND/1024) scan blocks
#define NT_ALL 18750 // ND/16 semantic tiles
#define HID 128
#define INC 64

typedef _Float16 half8 __attribute__((ext_vector_type(8)));
typedef float float4v __attribute__((ext_vector_type(4)));
typedef float floatx2 __attribute__((ext_vector_type(2)));

// ---------------------------------------------------------------------------
// Stage 1 (fused, MFMA): per node type, h = x @ W + b (fp8 e4m3, [N][128] B)
// and attention dots a_p = x @ (W·A_p) + b·A_p (fp32 [N][8]).
// mfma_f32_16x16x32_f16: A[m=lane&15][k=(lane>>4)*8+j]; B[k][n=lane&15];
// C: col=lane&15, row=(lane>>4)*4+reg.
// ---------------------------------------------------------------------------
struct PT {
    const float* x; const float* W; const float* bias; unsigned char* h;
    const float* av0; const float* av1; const float* av2; const float* av3;
    float* ao0; float* ao1; float* ao2; float* ao3;
    int N; int ntiles; int bstart; int nblocks;
};

#define WPAD 72   // halves; row stride 144 B (16B-aligned b128 frags)
#define HPAD 136  // halves; row stride 272 B (16B-aligned b128 reads)

__global__ __launch_bounds__(256) void proj_mfma(PT t0, PT t1, PT t2)
{
    __shared__ _Float16 WT[128 * WPAD];    // 18.4 KB: WT[f][g] = W[g][f]
    __shared__ _Float16 AdT[32 * WPAD];    // 4.6 KB: (W·A)^T [c][g]
    __shared__ _Float16 ht[4][16][HPAD];   // 17.4 KB: per-wave h tile (f16)
    const int tid = threadIdx.x;
    const int lane = tid & 63, wv = tid >> 6;
    const int fi = lane & 15, hi = lane >> 4;

    PT A = (blockIdx.x >= t2.bstart) ? t2 : (blockIdx.x >= t1.bstart) ? t1 : t0;

    for (int idx = tid; idx < 64 * 128; idx += 256) {
        int g = idx >> 7, f = idx & 127;
        WT[f * WPAD + g] = (_Float16)A.W[idx];
    }
    __syncthreads();
    const float* avs[4] = {A.av0, A.av1, A.av2, A.av3};
    for (int idx = tid; idx < 32 * 64; idx += 256) {
        int c = idx & 31, g = idx >> 5;
        const float* av = avs[c >> 3];
        float v = 0.f;
        if (av) {
            int hh = c & 7;
#pragma unroll
            for (int d = 0; d < 16; ++d)
                v += (float)WT[(hh * 16 + d) * WPAD + g] * av[hh * 16 + d];
        }
        AdT[c * WPAD + g] = (_Float16)v;
    }
    __syncthreads();

    // persistent B fragments (K=64 -> 2 k-blocks)
    half8 bfr[8][2], bd[2][2];
#pragma unroll
    for (int nt = 0; nt < 8; ++nt)
#pragma unroll
        for (int kb = 0; kb < 2; ++kb)
            bfr[nt][kb] = *(const half8*)&WT[(nt * 16 + fi) * WPAD + kb * 32 + hi * 8];
#pragma unroll
    for (int t = 0; t < 2; ++t)
#pragma unroll
        for (int kb = 0; kb < 2; ++kb)
            bd[t][kb] = *(const half8*)&AdT[(t * 16 + fi) * WPAD + kb * 32 + hi * 8];

    float bvv[8];
#pragma unroll
    for (int nt = 0; nt < 8; ++nt) bvv[nt] = A.bias[nt * 16 + fi];
    float bdc[2] = {0.f, 0.f};
    {
        int hh = fi & 7;
        const float* alo = (fi >= 8) ? A.av1 : A.av0;
        const float* ahi = (fi >= 8) ? A.av3 : A.av2;
#pragma unroll
        for (int d = 0; d < 16; ++d) {
            float bb = A.bias[hh * 16 + d];
            if (alo) bdc[0] += bb * alo[hh * 16 + d];
            if (ahi) bdc[1] += bb * ahi[hh * 16 + d];
        }
    }
    float* aolo = (fi >= 8) ? A.ao1 : A.ao0;
    float* aohi = (fi >= 8) ? A.ao3 : A.ao2;
    const bool has_hi = (A.av2 != nullptr) || (A.av3 != nullptr);

    const int stride = A.nblocks * 4;
    for (int t = (blockIdx.x - A.bstart) * 4 + wv; t < A.ntiles; t += stride) {
        const int base = t * 16;
        int rsrc = base + fi; if (rsrc >= A.N) rsrc = A.N - 1;
        const float* xp = A.x + (size_t)rsrc * 64 + hi * 8;
        float4 u0 = *(const float4*)(xp);
        float4 u1 = *(const float4*)(xp + 4);
        float4 u2 = *(const float4*)(xp + 32);
        float4 u3 = *(const float4*)(xp + 36);
        half8 a0, a1;
        a0[0] = (_Float16)u0.x; a0[1] = (_Float16)u0.y; a0[2] = (_Float16)u0.z; a0[3] = (_Float16)u0.w;
        a0[4] = (_Float16)u1.x; a0[5] = (_Float16)u1.y; a0[6] = (_Float16)u1.z; a0[7] = (_Float16)u1.w;
        a1[0] = (_Float16)u2.x; a1[1] = (_Float16)u2.y; a1[2] = (_Float16)u2.z; a1[3] = (_Float16)u2.w;
        a1[4] = (_Float16)u3.x; a1[5] = (_Float16)u3.y; a1[6] = (_Float16)u3.z; a1[7] = (_Float16)u3.w;

        float4v c[8];
#pragma unroll
        for (int nt = 0; nt < 8; ++nt) {
            float4v z = {0.f, 0.f, 0.f, 0.f};
            z = __builtin_amdgcn_mfma_f32_16x16x32_f16(a0, bfr[nt][0], z, 0, 0, 0);
            z = __builtin_amdgcn_mfma_f32_16x16x32_f16(a1, bfr[nt][1], z, 0, 0, 0);
            c[nt] = z;
        }
        float4v d0 = {0.f, 0.f, 0.f, 0.f};
        d0 = __builtin_amdgcn_mfma_f32_16x16x32_f16(a0, bd[0][0], d0, 0, 0, 0);
        d0 = __builtin_amdgcn_mfma_f32_16x16x32_f16(a1, bd[0][1], d0, 0, 0, 0);
        float4v d1 = {0.f, 0.f, 0.f, 0.f};
        if (has_hi) {
            d1 = __builtin_amdgcn_mfma_f32_16x16x32_f16(a0, bd[1][0], d1, 0, 0, 0);
            d1 = __builtin_amdgcn_mfma_f32_16x16x32_f16(a1, bd[1][1], d1, 0, 0, 0);
        }

        // h epilogue: C frags -> per-wave LDS tile -> fp8 coalesced stores
#pragma unroll
        for (int nt = 0; nt < 8; ++nt)
#pragma unroll
            for (int r = 0; r < 4; ++r)
                ht[wv][hi * 4 + r][nt * 16 + fi] = (_Float16)(c[nt][r] + bvv[nt]);
#pragma unroll
        for (int i = 0; i < 4; ++i) {
            int row = i * 4 + hi;
            int node = base + row;
            if (node < A.N) {
                half8 v = *(const half8*)&ht[wv][row][fi * 8];
                int pa = __builtin_amdgcn_cvt_pk_fp8_f32((float)v[0], (float)v[1], 0, false);
                pa = __builtin_amdgcn_cvt_pk_fp8_f32((float)v[2], (float)v[3], pa, true);
                int pb = __builtin_amdgcn_cvt_pk_fp8_f32((float)v[4], (float)v[5], 0, false);
                pb = __builtin_amdgcn_cvt_pk_fp8_f32((float)v[6], (float)v[7], pb, true);
                int2 o = {pa, pb};
                *(int2*)(A.h + (size_t)node * 128 + fi * 8) = o;
            }
        }
        if (aolo) {
#pragma unroll
            for (int r = 0; r < 4; ++r) {
                int node = base + hi * 4 + r;
                if (node < A.N) aolo[(size_t)node * 8 + (fi & 7)] = d0[r] + bdc[0];
            }
        }
        if (aohi) {
#pragma unroll
            for (int r = 0; r < 4; ++r) {
                int node = base + hi * 4 + r;
                if (node < A.N) aohi[(size_t)node * 8 + (fi & 7)] = d1[r] + bdc[1];
            }
        }
    }
}

// ---------------------------------------------------------------------------
// CSR build over the concatenated (edge-type, dst) slot space.
// ---------------------------------------------------------------------------
__device__ __forceinline__ void decode_edge(
    int e, const int* ei00, const int* ei10, const int* ei11, const int* ei21,
    int& src, int& slot)
{
    if (e < E00)                    { src = ei00[e];               slot = ei00[E00 + e]; }
    else if (e < E00 + E10)         { int i = e - E00;             src = ei10[i]; slot = 50000  + ei10[E10 + i]; }
    else if (e < E00 + E10 + E11)   { int i = e - E00 - E10;       src = ei11[i]; slot = 100000 + ei11[E11 + i]; }
    else                            { int i = e - E00 - E10 - E11; src = ei21[i]; slot = 200000 + ei21[E21 + i]; }
}

__global__ __launch_bounds__(256) void count_kernel(
    const int* __restrict__ ei00, const int* __restrict__ ei10,
    const int* __restrict__ ei11, const int* __restrict__ ei21,
    int* __restrict__ cnt)
{
    int e = blockIdx.x * 256 + threadIdx.x;
    if (e >= EE) return;
    int src, slot;
    decode_edge(e, ei00, ei10, ei11, ei21, src, slot);
    atomicAdd(&cnt[slot], 1);
}

__global__ __launch_bounds__(256) void scan1_kernel(
    const int* __restrict__ cnt, int* __restrict__ part)
{
    const int tid = threadIdx.x, b = blockIdx.x;
    int i0 = b * 1024 + tid * 4;
    int s = 0;
#pragma unroll
    for (int k = 0; k < 4; ++k) { int i = i0 + k; s += (i < ND) ? cnt[i] : 0; }
#pragma unroll
    for (int off = 1; off < 64; off <<= 1) s += __shfl_xor(s, off);
    __shared__ int wt[4];
    if ((tid & 63) == 0) wt[tid >> 6] = s;
    __syncthreads();
    if (tid == 0) part[b] = wt[0] + wt[1] + wt[2] + wt[3];
}

__global__ __launch_bounds__(256) void scan2_kernel(int* __restrict__ part)
{
    const int t = threadIdx.x;
    int p0 = (2 * t     < NB) ? part[2 * t]     : 0;
    int p1 = (2 * t + 1 < NB) ? part[2 * t + 1] : 0;
    int ps = p0 + p1;
    __shared__ int sd[256];
    sd[t] = ps; __syncthreads();
    for (int d = 1; d < 256; d <<= 1) {
        int v = (t >= d) ? sd[t - d] : 0;
        __syncthreads();
        sd[t] += v;
        __syncthreads();
    }
    int exc = sd[t] - ps;
    if (2 * t     < NB) part[2 * t]     = exc;
    if (2 * t + 1 < NB) part[2 * t + 1] = exc + p0;
}

__global__ __launch_bounds__(256) void scan3_kernel(
    const int* __restrict__ cnt, const int* __restrict__ part,
    int* __restrict__ off, int* __restrict__ cursor)
{
    const int tid = threadIdx.x, b = blockIdx.x;
    const int lane = tid & 63, wv = tid >> 6;
    int i0 = b * 1024 + tid * 4;
    int v[4];
#pragma unroll
    for (int k = 0; k < 4; ++k) { int i = i0 + k; v[k] = (i < ND) ? cnt[i] : 0; }
    int ts = v[0] + v[1] + v[2] + v[3];
    int inc = ts;
#pragma unroll
    for (int d = 1; d < 64; d <<= 1) {
        int u = __shfl_up(inc, d);
        if (lane >= d) inc += u;
    }
    int wexc = inc - ts;
    __shared__ int wt[4];
    if (lane == 63) wt[wv] = inc;
    __syncthreads();
    int wbase = 0;
    for (int w = 0; w < wv; ++w) wbase += wt[w];
    int base = part[b] + wbase + wexc;
    int pre = 0;
#pragma unroll
    for (int k = 0; k < 4; ++k) {
        int i = i0 + k;
        if (i < ND) { off[i] = base + pre; cursor[i] = base + pre; }
        pre += v[k];
    }
}

// ---------------------------------------------------------------------------
// Fill: place src ids in CSR order AND precompute the 8 per-head softmax
// numerators w = exp(leaky_relu(a_s + a_d)) for each edge (f16x8, CSR order).
// ---------------------------------------------------------------------------
__global__ __launch_bounds__(256) void fill_kernel(
    const int* __restrict__ ei00, const int* __restrict__ ei10,
    const int* __restrict__ ei11, const int* __restrict__ ei21,
    const float* __restrict__ as00, const float* __restrict__ ad00,
    const float* __restrict__ as10, const float* __restrict__ ad10,
    const float* __restrict__ as11, const float* __restrict__ ad11,
    const float* __restrict__ as21, const float* __restrict__ ad21,
    int* __restrict__ cursor, int* __restrict__ srcs, _Float16* __restrict__ wgt)
{
    int e = blockIdx.x * 256 + threadIdx.x;
    if (e >= EE) return;
    int src, d, slot;
    const float* asp; const float* adp;
    if (e < E00) {
        src = ei00[e]; d = ei00[E00 + e]; slot = d; asp = as00; adp = ad00;
    } else if (e < E00 + E10) {
        int i = e - E00; src = ei10[i]; d = ei10[E10 + i]; slot = 50000 + d; asp = as10; adp = ad10;
    } else if (e < E00 + E10 + E11) {
        int i = e - E00 - E10; src = ei11[i]; d = ei11[E11 + i]; slot = 100000 + d; asp = as11; adp = ad11;
    } else {
        int i = e - E00 - E10 - E11; src = ei21[i]; d = ei21[E21 + i]; slot = 200000 + d; asp = as21; adp = ad21;
    }
    float4 sa0 = *(const float4*)(asp + (size_t)src * 8);
    float4 sa1 = *(const float4*)(asp + (size_t)src * 8 + 4);
    float4 da0 = *(const float4*)(adp + (size_t)d * 8);
    float4 da1 = *(const float4*)(adp + (size_t)d * 8 + 4);
    float vv[8] = {sa0.x + da0.x, sa0.y + da0.y, sa0.z + da0.z, sa0.w + da0.w,
                   sa1.x + da1.x, sa1.y + da1.y, sa1.z + da1.z, sa1.w + da1.w};
    half8 w;
#pragma unroll
    for (int h = 0; h < 8; ++h) {
        float v = vv[h];
        v = v > 0.f ? v : 0.2f * v;
        w[h] = (_Float16)__expf(v);
    }
    int pos = atomicAdd(&cursor[slot], 1);
    srcs[pos] = src;
    *(half8*)(wgt + (size_t)pos * 8) = w;
}

// ---------------------------------------------------------------------------
// Gather: 4 slots per wave, 16 lanes per slot; lane covers 8 fp8 features
// (one b64 load per edge), head = (lane&15)>>1. Weights read sequentially
// from the CSR-ordered wgt array. agg (fp8, relu'ed) written exactly once.
// ---------------------------------------------------------------------------
__global__ __launch_bounds__(256) void gather_kernel(
    const int* __restrict__ cnt, const int* __restrict__ off,
    const int* __restrict__ srcs, const _Float16* __restrict__ wgt,
    const unsigned char* __restrict__ h0, const unsigned char* __restrict__ h1,
    const unsigned char* __restrict__ h2,
    unsigned char* __restrict__ agg)
{
    const int gid = blockIdx.x * 256 + threadIdx.x;
    const int lane = gid & 63;
    const int grp = lane >> 4, lg = lane & 15;
    const int slot = (gid >> 6) * 4 + grp;          // grid sized so slot < ND
    const int head = lg >> 1;
    const unsigned char* hs = (slot < 50000) ? h0 : (slot < 200000) ? h1 : h2;
    const int deg = cnt[slot], st = off[slot];

    int degm = deg;
    degm = max(degm, __shfl_xor(degm, 16));
    degm = max(degm, __shfl_xor(degm, 32));

    float acc[8] = {0.f, 0.f, 0.f, 0.f, 0.f, 0.f, 0.f, 0.f};
    float sw = 0.f;
    int i = 0;
    for (; i + 2 <= degm; i += 2) {
        bool a0 = (i < deg), a1 = (i + 1 < deg);
        int s0 = 0, s1 = 0;
        if (a0) s0 = srcs[st + i];
        if (a1) s1 = srcs[st + i + 1];
        float w0 = 0.f, w1 = 0.f;
        unsigned long long v0 = 0, v1 = 0;
        if (a0) { w0 = (float)wgt[(size_t)(st + i) * 8 + head];
                  v0 = *(const unsigned long long*)(hs + (size_t)s0 * 128 + lg * 8); }
        if (a1) { w1 = (float)wgt[(size_t)(st + i + 1) * 8 + head];
                  v1 = *(const unsigned long long*)(hs + (size_t)s1 * 128 + lg * 8); }
        int l0 = (int)(v0 & 0xffffffffu), m0 = (int)(v0 >> 32);
        int l1 = (int)(v1 & 0xffffffffu), m1 = (int)(v1 >> 32);
        floatx2 f0a = __builtin_amdgcn_cvt_pk_f32_fp8(l0, false);
        floatx2 f0b = __builtin_amdgcn_cvt_pk_f32_fp8(l0, true);
        floatx2 f0c = __builtin_amdgcn_cvt_pk_f32_fp8(m0, false);
        floatx2 f0d = __builtin_amdgcn_cvt_pk_f32_fp8(m0, true);
        floatx2 f1a = __builtin_amdgcn_cvt_pk_f32_fp8(l1, false);
        floatx2 f1b = __builtin_amdgcn_cvt_pk_f32_fp8(l1, true);
        floatx2 f1c = __builtin_amdgcn_cvt_pk_f32_fp8(m1, false);
        floatx2 f1d = __builtin_amdgcn_cvt_pk_f32_fp8(m1, true);
        acc[0] += w0 * f0a.x + w1 * f1a.x;
        acc[1] += w0 * f0a.y + w1 * f1a.y;
        acc[2] += w0 * f0b.x + w1 * f1b.x;
        acc[3] += w0 * f0b.y + w1 * f1b.y;
        acc[4] += w0 * f0c.x + w1 * f1c.x;
        acc[5] += w0 * f0c.y + w1 * f1c.y;
        acc[6] += w0 * f0d.x + w1 * f1d.x;
        acc[7] += w0 * f0d.y + w1 * f1d.y;
        sw += w0 + w1;
    }
    if (i < degm) {
        bool a0 = (i < deg);
        int s0 = 0;
        if (a0) s0 = srcs[st + i];
        float w0 = 0.f;
        unsigned long long v0 = 0;
        if (a0) { w0 = (float)wgt[(size_t)(st + i) * 8 + head];
                  v0 = *(const unsigned long long*)(hs + (size_t)s0 * 128 + lg * 8); }
        int l0 = (int)(v0 & 0xffffffffu), m0 = (int)(v0 >> 32);
        floatx2 f0a = __builtin_amdgcn_cvt_pk_f32_fp8(l0, false);
        floatx2 f0b = __builtin_amdgcn_cvt_pk_f32_fp8(l0, true);
        floatx2 f0c = __builtin_amdgcn_cvt_pk_f32_fp8(m0, false);
        floatx2 f0d = __builtin_amdgcn_cvt_pk_f32_fp8(m0, true);
        acc[0] += w0 * f0a.x; acc[1] += w0 * f0a.y;
        acc[2] += w0 * f0b.x; acc[3] += w0 * f0b.y;
        acc[4] += w0 * f0c.x; acc[5] += w0 * f0c.y;
        acc[6] += w0 * f0d.x; acc[7] += w0 * f0d.y;
        sw += w0;
    }

    float rr = __builtin_amdgcn_rcpf(sw + 1e-16f);
    float r[8];
#pragma unroll
    for (int j = 0; j < 8; ++j) r[j] = fmaxf(acc[j] * rr, 0.f);   // relu here
    int pa = __builtin_amdgcn_cvt_pk_fp8_f32(r[0], r[1], 0, false);
    pa = __builtin_amdgcn_cvt_pk_fp8_f32(r[2], r[3], pa, true);
    int pb = __builtin_amdgcn_cvt_pk_fp8_f32(r[4], r[5], 0, false);
    pb = __builtin_amdgcn_cvt_pk_fp8_f32(r[6], r[7], pb, true);
    int2 o = {pa, pb};
    *(int2*)(agg + (size_t)slot * 128 + lg * 8) = o;
}

// ---------------------------------------------------------------------------
// Stage 4 (fused, fp8 MFMA): Y = agg_relu @ [k_w | lin_w], f-tiles SPLIT
// ACROSS THE 4 WAVES of the block (wv0:{0,1} wv1:{2,3} wv2:{4,5}
// wv3:{6,7,8}) so each wave's B fragments (16-24 VGPRs) stay register-
// resident — the score is separable per f-column. All 4 waves read the same
// 2 KB agg tile (L1-shared). metapath of tile t: 3=t>=12500, 2=t>=6250,
// 1=t>=3125, else 0 (u00,b10,u11,b21).
// ---------------------------------------------------------------------------
#define KSTRB 136
__global__ __launch_bounds__(256, 4) void semantic_kernel(
    const unsigned char* __restrict__ agg,
    const float* __restrict__ kw, const float* __restrict__ lw,
    const float* __restrict__ kb, const float* __restrict__ q,
    float* __restrict__ cs2, float* __restrict__ score)
{
    __shared__ unsigned char kwT[144 * KSTRB];   // 19.6 KB fp8, f-major
    __shared__ float redv[12];
    const int tid = threadIdx.x;
    const int lane = tid & 63, wv = tid >> 6;
    const int fi = lane & 15, hi = lane >> 4;

    for (int idx = tid; idx < 128 * 128; idx += 256) {
        int g = idx >> 7, f = idx & 127;
        int r = __builtin_amdgcn_cvt_pk_fp8_f32(kw[idx], 0.f, 0, false);
        kwT[f * KSTRB + g] = (unsigned char)r;
    }
    for (int idx = tid; idx < 16 * 128; idx += 256) {
        int f2 = idx >> 7, g = idx & 127;
        float v = (f2 < 2) ? lw[g * 2 + f2] : 0.f;
        int r = __builtin_amdgcn_cvt_pk_fp8_f32(v, 0.f, 0, false);
        kwT[(128 + f2) * KSTRB + g] = (unsigned char)r;
    }
    if (tid < 12) redv[tid] = 0.f;
    __syncthreads();

    // this wave's f-tiles
    const int ftbase = wv * 2;
    const int nft = (wv == 3) ? 3 : 2;

    long bf[3][4];
    float qv[3], kbv[3];
#pragma unroll
    for (int i = 0; i < 3; ++i) {
        if (i < nft) {
            int ft = ftbase + i;
#pragma unroll
            for (int kk = 0; kk < 4; ++kk)
                bf[i][kk] = *(const long*)&kwT[(ft * 16 + fi) * KSTRB + kk * 32 + hi * 8];
            qv[i]  = (ft < 8) ? q[ft * 16 + fi]  : 0.f;
            kbv[i] = (ft < 8) ? kb[ft * 16 + fi] : 0.f;
        } else {
            bf[i][0] = bf[i][1] = bf[i][2] = bf[i][3] = 0;
            qv[i] = 0.f; kbv[i] = 0.f;
        }
    }

    float sc[4] = {0.f, 0.f, 0.f, 0.f};
    float cs[4] = {0.f, 0.f, 0.f, 0.f};
    for (int t = blockIdx.x; t < NT_ALL; t += gridDim.x) {
        const int m = (t >= 12500) ? 3 : (t >= 6250) ? 2 : (t >= 3125) ? 1 : 0;
        const unsigned char* rowp = agg + ((size_t)(t * 16 + fi) * 128 + hi * 8);
        long af[4];
        af[0] = *(const long*)(rowp);
        af[1] = *(const long*)(rowp + 32);
        af[2] = *(const long*)(rowp + 64);
        af[3] = *(const long*)(rowp + 96);
        float tsc = 0.f, tcs = 0.f;
#pragma unroll
        for (int i = 0; i < 3; ++i) {
            if (i >= nft) continue;
            float4v c = {0.f, 0.f, 0.f, 0.f};
            c = __builtin_amdgcn_mfma_f32_16x16x32_fp8_fp8(af[0], bf[i][0], c, 0, 0, 0);
            c = __builtin_amdgcn_mfma_f32_16x16x32_fp8_fp8(af[1], bf[i][1], c, 0, 0, 0);
            c = __builtin_amdgcn_mfma_f32_16x16x32_fp8_fp8(af[2], bf[i][2], c, 0, 0, 0);
            c = __builtin_amdgcn_mfma_f32_16x16x32_fp8_fp8(af[3], bf[i][3], c, 0, 0, 0);
            if (ftbase + i == 8) {
                tcs = c[0] + c[1] + c[2] + c[3];
            } else {
#pragma unroll
                for (int r = 0; r < 4; ++r) {
                    float y = c[r] + kbv[i];
                    float e = __expf(2.f * y);
                    tsc += qv[i] * (1.f - 2.f * __builtin_amdgcn_rcpf(e + 1.f));
                }
            }
        }
        if (m == 0)      { sc[0] += tsc; cs[0] += tcs; }
        else if (m == 1) { sc[1] += tsc; cs[1] += tcs; }
        else if (m == 2) { sc[2] += tsc; cs[2] += tcs; }
        else             { sc[3] += tsc; cs[3] += tcs; }
    }

#pragma unroll
    for (int m = 0; m < 4; ++m) {
        float s = sc[m];
#pragma unroll
        for (int off = 1; off < 64; off <<= 1) s += __shfl_xor(s, off);
        if (lane == 0 && s != 0.f) atomicAdd(&redv[m], s);
        float v = cs[m];
        v += __shfl_xor(v, 16);
        v += __shfl_xor(v, 32);
        if (hi == 0 && fi < 2 && v != 0.f) atomicAdd(&redv[4 + 2 * m + fi], v);
    }
    __syncthreads();
    if (tid < 4)              atomicAdd(&score[tid], redv[tid]);
    if (tid >= 4 && tid < 12) atomicAdd(&cs2[tid - 4], redv[tid]);
}

// ---------------------------------------------------------------------------
// Stage 5: semantic softmax + classifier + sigmoid. One thread.
// ---------------------------------------------------------------------------
__global__ void final_kernel(const float* __restrict__ cs2,
                             const float* __restrict__ score,
                             const float* __restrict__ lb,
                             float* __restrict__ out)
{
    float s0 = score[0] / (float)N0;
    float s1 = score[1] / (float)N0;
    float s2 = score[2] / (float)N1;
    float s3 = score[3] / (float)N1;
    float m0 = fmaxf(s0, s1);
    float e0 = expf(s0 - m0), e1 = expf(s1 - m0);
    float a0 = e0 / (e0 + e1), a1 = e1 / (e0 + e1);
    float m1 = fmaxf(s2, s3);
    float e2 = expf(s2 - m1), e3 = expf(s3 - m1);
    float a2 = e2 / (e2 + e3), a3 = e3 / (e2 + e3);
    float z0 = a0 * cs2[0] + a1 * cs2[2] + a2 * cs2[4] + a3 * cs2[6] + lb[0];
    float z1 = a0 * cs2[1] + a1 * cs2[3] + a2 * cs2[5] + a3 * cs2[7] + lb[1];
    out[0] = 1.f / (1.f + expf(-z0));
    out[1] = 1.f / (1.f + expf(-z1));
}

extern "C" void kernel_launch(void* const* d_in, const int* in_sizes, int n_in,
                              void* d_out, int out_size, void* d_ws, size_t ws_size,
                              hipStream_t stream)
{
    const float* x0  = (const float*)d_in[0];
    const float* x1  = (const float*)d_in[1];
    const float* x2  = (const float*)d_in[2];
    const int* ei00  = (const int*)d_in[3];
    const int* ei11  = (const int*)d_in[4];
    const int* ei10  = (const int*)d_in[5];
    const int* ei21  = (const int*)d_in[6];
    const float* W0  = (const float*)d_in[7];  const float* b0 = (const float*)d_in[8];
    const float* W1  = (const float*)d_in[9];  const float* b1 = (const float*)d_in[10];
    const float* W2  = (const float*)d_in[11]; const float* b2 = (const float*)d_in[12];
    const float* as00 = (const float*)d_in[13]; const float* ad00 = (const float*)d_in[14];
    const float* as11 = (const float*)d_in[15]; const float* ad11 = (const float*)d_in[16];
    const float* as10 = (const float*)d_in[17]; const float* ad10 = (const float*)d_in[18];
    const float* as21 = (const float*)d_in[19]; const float* ad21 = (const float*)d_in[20];
    const float* kw  = (const float*)d_in[21]; const float* kb  = (const float*)d_in[22];
    const float* q   = (const float*)d_in[23];
    const float* lw  = (const float*)d_in[24]; const float* lb  = (const float*)d_in[25];
    float* out = (float*)d_out;

    char* p = (char*)d_ws;
    auto alloc = [&](size_t bytes) {
        char* r = p;
        p += (bytes + 255) & ~(size_t)255;
        return r;
    };
    unsigned char* h0 = (unsigned char*)alloc((size_t)N0 * 128);   // fp8 [N][128]
    unsigned char* h1 = (unsigned char*)alloc((size_t)N1 * 128);
    unsigned char* h2 = (unsigned char*)alloc((size_t)N2 * 128);
    float* o_as00 = (float*)alloc((size_t)N0 * 32);
    float* o_ad00 = (float*)alloc((size_t)N0 * 32);
    float* o_as11 = (float*)alloc((size_t)N1 * 32);
    float* o_ad11 = (float*)alloc((size_t)N1 * 32);
    float* o_as10 = (float*)alloc((size_t)N1 * 32);   // src of b10 = cell1
    float* o_ad10 = (float*)alloc((size_t)N0 * 32);   // dst of b10 = cell0
    float* o_as21 = (float*)alloc((size_t)N2 * 32);   // src of b21 = cell2
    float* o_ad21 = (float*)alloc((size_t)N1 * 32);   // dst of b21 = cell1
    int* off    = (int*)alloc((size_t)ND * 4);
    int* cursor = (int*)alloc((size_t)ND * 4);
    int* part   = (int*)alloc((size_t)512 * 4);
    int* srcs   = (int*)alloc((size_t)EE * 4);
    _Float16* wgt = (_Float16*)alloc((size_t)EE * 16);             // f16x8 per edge
    unsigned char* agg = (unsigned char*)alloc((size_t)ND * 128);  // fp8 [u00|b10|u11|b21]
    // ---- zero region (contiguous) ----
    char* zstart = p;
    int* cnt = (int*)alloc((size_t)ND * 4);
    float* colsum2 = (float*)alloc(8 * 4);
    float* score   = (float*)alloc(4 * 4);
    size_t zbytes = (size_t)(p - zstart);

    (void)hipMemsetAsync(zstart, 0, zbytes, stream);

    // fused MFMA projection: blocks [0,148) cell0, [148,440) cell1, [440,512) cell2
    PT t0 = {x0, W0, b0, h0,
             as00, ad00, ad10, nullptr,
             o_as00, o_ad00, o_ad10, nullptr,
             N0, 3125, 0, 148};
    PT t1 = {x1, W1, b1, h1,
             as11, ad11, as10, ad21,
             o_as11, o_ad11, o_as10, o_ad21,
             N1, 6250, 148, 292};
    PT t2 = {x2, W2, b2, h2,
             as21, nullptr, nullptr, nullptr,
             o_as21, nullptr, nullptr, nullptr,
             N2, 1563, 440, 72};
    proj_mfma<<<512, 256, 0, stream>>>(t0, t1, t2);

    // CSR build
    count_kernel<<<(EE + 255) / 256, 256, 0, stream>>>(ei00, ei10, ei11, ei21, cnt);
    scan1_kernel<<<NB, 256, 0, stream>>>(cnt, part);
    scan2_kernel<<<1, 256, 0, stream>>>(part);
    scan3_kernel<<<NB, 256, 0, stream>>>(cnt, part, off, cursor);
    fill_kernel<<<(EE + 255) / 256, 256, 0, stream>>>(ei00, ei10, ei11, ei21,
        o_as00, o_ad00, o_as10, o_ad10, o_as11, o_ad11, o_as21, o_ad21,
        cursor, srcs, wgt);

    // gather (4 slots/wave, CSR-ordered weights, fp8 h rows)
    gather_kernel<<<ND / 16, 256, 0, stream>>>(cnt, off, srcs, wgt, h0, h1, h2, agg);

    // fused semantic reduction over all 4 metapaths (fp8 MFMA, wave-split f-tiles)
    semantic_kernel<<<1536, 256, 0, stream>>>(agg, kw, lw, kb, q, colsum2, score);

    final_kernel<<<1, 1, 0, stream>>>(colsum2, score, lb, out);
}

// Round 9
// 315.431 us; speedup vs baseline: 1.0867x; 1.0867x over previous
//
#include <hip/hip_runtime.h>
#include <hip/hip_fp16.h>

#define N0 50000
#define N1 100000
#define N2 25000
#define E00 200000
#define E11 200000
#define E10 100000
#define E21 50000
#define EE  550000   // E00+E10+E11+E21 (concatenated edge space)
#define ND  300000   // 50000(u00)+50000(b10)+100000(u11)+100000(b21) dst slots
#define NB  293      // ceil(ND/1024) scan blocks
#define NT_ALL 18750 // ND/16 semantic tiles
#define HID 128
#define INC 64

typedef _Float16 half8 __attribute__((ext_vector_type(8)));
typedef float float4v __attribute__((ext_vector_type(4)));
typedef float floatx2 __attribute__((ext_vector_type(2)));

// ---------------------------------------------------------------------------
// Stage 1 (fused, MFMA): per node type, h = x @ W + b (fp8 e4m3, [N][128] B)
// and attention dots a_p = x @ (W·A_p) + b·A_p (fp32 [N][8]).
// mfma_f32_16x16x32_f16: A[m=lane&15][k=(lane>>4)*8+j]; B[k][n=lane&15];
// C: col=lane&15, row=(lane>>4)*4+reg.
// ---------------------------------------------------------------------------
struct PT {
    const float* x; const float* W; const float* bias; unsigned char* h;
    const float* av0; const float* av1; const float* av2; const float* av3;
    float* ao0; float* ao1; float* ao2; float* ao3;
    int N; int ntiles; int bstart; int nblocks;
};

#define WPAD 72   // halves; row stride 144 B (16B-aligned b128 frags)
#define HPAD 136  // halves; row stride 272 B (16B-aligned b128 reads)

__global__ __launch_bounds__(256) void proj_mfma(PT t0, PT t1, PT t2)
{
    __shared__ _Float16 WT[128 * WPAD];    // 18.4 KB: WT[f][g] = W[g][f]
    __shared__ _Float16 AdT[32 * WPAD];    // 4.6 KB: (W·A)^T [c][g]
    __shared__ _Float16 ht[4][16][HPAD];   // 17.4 KB: per-wave h tile (f16)
    const int tid = threadIdx.x;
    const int lane = tid & 63, wv = tid >> 6;
    const int fi = lane & 15, hi = lane >> 4;

    PT A = (blockIdx.x >= t2.bstart) ? t2 : (blockIdx.x >= t1.bstart) ? t1 : t0;

    for (int idx = tid; idx < 64 * 128; idx += 256) {
        int g = idx >> 7, f = idx & 127;
        WT[f * WPAD + g] = (_Float16)A.W[idx];
    }
    __syncthreads();
    const float* avs[4] = {A.av0, A.av1, A.av2, A.av3};
    for (int idx = tid; idx < 32 * 64; idx += 256) {
        int c = idx & 31, g = idx >> 5;
        const float* av = avs[c >> 3];
        float v = 0.f;
        if (av) {
            int hh = c & 7;
#pragma unroll
            for (int d = 0; d < 16; ++d)
                v += (float)WT[(hh * 16 + d) * WPAD + g] * av[hh * 16 + d];
        }
        AdT[c * WPAD + g] = (_Float16)v;
    }
    __syncthreads();

    // persistent B fragments (K=64 -> 2 k-blocks)
    half8 bfr[8][2], bd[2][2];
#pragma unroll
    for (int nt = 0; nt < 8; ++nt)
#pragma unroll
        for (int kb = 0; kb < 2; ++kb)
            bfr[nt][kb] = *(const half8*)&WT[(nt * 16 + fi) * WPAD + kb * 32 + hi * 8];
#pragma unroll
    for (int t = 0; t < 2; ++t)
#pragma unroll
        for (int kb = 0; kb < 2; ++kb)
            bd[t][kb] = *(const half8*)&AdT[(t * 16 + fi) * WPAD + kb * 32 + hi * 8];

    float bvv[8];
#pragma unroll
    for (int nt = 0; nt < 8; ++nt) bvv[nt] = A.bias[nt * 16 + fi];
    float bdc[2] = {0.f, 0.f};
    {
        int hh = fi & 7;
        const float* alo = (fi >= 8) ? A.av1 : A.av0;
        const float* ahi = (fi >= 8) ? A.av3 : A.av2;
#pragma unroll
        for (int d = 0; d < 16; ++d) {
            float bb = A.bias[hh * 16 + d];
            if (alo) bdc[0] += bb * alo[hh * 16 + d];
            if (ahi) bdc[1] += bb * ahi[hh * 16 + d];
        }
    }
    float* aolo = (fi >= 8) ? A.ao1 : A.ao0;
    float* aohi = (fi >= 8) ? A.ao3 : A.ao2;
    const bool has_hi = (A.av2 != nullptr) || (A.av3 != nullptr);

    const int stride = A.nblocks * 4;
    for (int t = (blockIdx.x - A.bstart) * 4 + wv; t < A.ntiles; t += stride) {
        const int base = t * 16;
        int rsrc = base + fi; if (rsrc >= A.N) rsrc = A.N - 1;
        const float* xp = A.x + (size_t)rsrc * 64 + hi * 8;
        float4 u0 = *(const float4*)(xp);
        float4 u1 = *(const float4*)(xp + 4);
        float4 u2 = *(const float4*)(xp + 32);
        float4 u3 = *(const float4*)(xp + 36);
        half8 a0, a1;
        a0[0] = (_Float16)u0.x; a0[1] = (_Float16)u0.y; a0[2] = (_Float16)u0.z; a0[3] = (_Float16)u0.w;
        a0[4] = (_Float16)u1.x; a0[5] = (_Float16)u1.y; a0[6] = (_Float16)u1.z; a0[7] = (_Float16)u1.w;
        a1[0] = (_Float16)u2.x; a1[1] = (_Float16)u2.y; a1[2] = (_Float16)u2.z; a1[3] = (_Float16)u2.w;
        a1[4] = (_Float16)u3.x; a1[5] = (_Float16)u3.y; a1[6] = (_Float16)u3.z; a1[7] = (_Float16)u3.w;

        float4v c[8];
#pragma unroll
        for (int nt = 0; nt < 8; ++nt) {
            float4v z = {0.f, 0.f, 0.f, 0.f};
            z = __builtin_amdgcn_mfma_f32_16x16x32_f16(a0, bfr[nt][0], z, 0, 0, 0);
            z = __builtin_amdgcn_mfma_f32_16x16x32_f16(a1, bfr[nt][1], z, 0, 0, 0);
            c[nt] = z;
        }
        float4v d0 = {0.f, 0.f, 0.f, 0.f};
        d0 = __builtin_amdgcn_mfma_f32_16x16x32_f16(a0, bd[0][0], d0, 0, 0, 0);
        d0 = __builtin_amdgcn_mfma_f32_16x16x32_f16(a1, bd[0][1], d0, 0, 0, 0);
        float4v d1 = {0.f, 0.f, 0.f, 0.f};
        if (has_hi) {
            d1 = __builtin_amdgcn_mfma_f32_16x16x32_f16(a0, bd[1][0], d1, 0, 0, 0);
            d1 = __builtin_amdgcn_mfma_f32_16x16x32_f16(a1, bd[1][1], d1, 0, 0, 0);
        }

        // h epilogue: C frags -> per-wave LDS tile -> fp8 coalesced stores
#pragma unroll
        for (int nt = 0; nt < 8; ++nt)
#pragma unroll
            for (int r = 0; r < 4; ++r)
                ht[wv][hi * 4 + r][nt * 16 + fi] = (_Float16)(c[nt][r] + bvv[nt]);
#pragma unroll
        for (int i = 0; i < 4; ++i) {
            int row = i * 4 + hi;
            int node = base + row;
            if (node < A.N) {
                half8 v = *(const half8*)&ht[wv][row][fi * 8];
                int pa = __builtin_amdgcn_cvt_pk_fp8_f32((float)v[0], (float)v[1], 0, false);
                pa = __builtin_amdgcn_cvt_pk_fp8_f32((float)v[2], (float)v[3], pa, true);
                int pb = __builtin_amdgcn_cvt_pk_fp8_f32((float)v[4], (float)v[5], 0, false);
                pb = __builtin_amdgcn_cvt_pk_fp8_f32((float)v[6], (float)v[7], pb, true);
                int2 o = {pa, pb};
                *(int2*)(A.h + (size_t)node * 128 + fi * 8) = o;
            }
        }
        if (aolo) {
#pragma unroll
            for (int r = 0; r < 4; ++r) {
                int node = base + hi * 4 + r;
                if (node < A.N) aolo[(size_t)node * 8 + (fi & 7)] = d0[r] + bdc[0];
            }
        }
        if (aohi) {
#pragma unroll
            for (int r = 0; r < 4; ++r) {
                int node = base + hi * 4 + r;
                if (node < A.N) aohi[(size_t)node * 8 + (fi & 7)] = d1[r] + bdc[1];
            }
        }
    }
}

// ---------------------------------------------------------------------------
// CSR build over the concatenated (edge-type, dst) slot space.
// ---------------------------------------------------------------------------
__device__ __forceinline__ void decode_edge(
    int e, const int* ei00, const int* ei10, const int* ei11, const int* ei21,
    int& src, int& slot)
{
    if (e < E00)                    { src = ei00[e];               slot = ei00[E00 + e]; }
    else if (e < E00 + E10)         { int i = e - E00;             src = ei10[i]; slot = 50000  + ei10[E10 + i]; }
    else if (e < E00 + E10 + E11)   { int i = e - E00 - E10;       src = ei11[i]; slot = 100000 + ei11[E11 + i]; }
    else                            { int i = e - E00 - E10 - E11; src = ei21[i]; slot = 200000 + ei21[E21 + i]; }
}

__global__ __launch_bounds__(256) void count_kernel(
    const int* __restrict__ ei00, const int* __restrict__ ei10,
    const int* __restrict__ ei11, const int* __restrict__ ei21,
    int* __restrict__ cnt)
{
    int e = blockIdx.x * 256 + threadIdx.x;
    if (e >= EE) return;
    int src, slot;
    decode_edge(e, ei00, ei10, ei11, ei21, src, slot);
    atomicAdd(&cnt[slot], 1);
}

__global__ __launch_bounds__(256) void scan1_kernel(
    const int* __restrict__ cnt, int* __restrict__ part)
{
    const int tid = threadIdx.x, b = blockIdx.x;
    int i0 = b * 1024 + tid * 4;
    int s = 0;
#pragma unroll
    for (int k = 0; k < 4; ++k) { int i = i0 + k; s += (i < ND) ? cnt[i] : 0; }
#pragma unroll
    for (int off = 1; off < 64; off <<= 1) s += __shfl_xor(s, off);
    __shared__ int wt[4];
    if ((tid & 63) == 0) wt[tid >> 6] = s;
    __syncthreads();
    if (tid == 0) part[b] = wt[0] + wt[1] + wt[2] + wt[3];
}

__global__ __launch_bounds__(256) void scan2_kernel(int* __restrict__ part)
{
    const int t = threadIdx.x;
    int p0 = (2 * t     < NB) ? part[2 * t]     : 0;
    int p1 = (2 * t + 1 < NB) ? part[2 * t + 1] : 0;
    int ps = p0 + p1;
    __shared__ int sd[256];
    sd[t] = ps; __syncthreads();
    for (int d = 1; d < 256; d <<= 1) {
        int v = (t >= d) ? sd[t - d] : 0;
        __syncthreads();
        sd[t] += v;
        __syncthreads();
    }
    int exc = sd[t] - ps;
    if (2 * t     < NB) part[2 * t]     = exc;
    if (2 * t + 1 < NB) part[2 * t + 1] = exc + p0;
}

__global__ __launch_bounds__(256) void scan3_kernel(
    const int* __restrict__ cnt, const int* __restrict__ part,
    int* __restrict__ off, int* __restrict__ cursor)
{
    const int tid = threadIdx.x, b = blockIdx.x;
    const int lane = tid & 63, wv = tid >> 6;
    int i0 = b * 1024 + tid * 4;
    int v[4];
#pragma unroll
    for (int k = 0; k < 4; ++k) { int i = i0 + k; v[k] = (i < ND) ? cnt[i] : 0; }
    int ts = v[0] + v[1] + v[2] + v[3];
    int inc = ts;
#pragma unroll
    for (int d = 1; d < 64; d <<= 1) {
        int u = __shfl_up(inc, d);
        if (lane >= d) inc += u;
    }
    int wexc = inc - ts;
    __shared__ int wt[4];
    if (lane == 63) wt[wv] = inc;
    __syncthreads();
    int wbase = 0;
    for (int w = 0; w < wv; ++w) wbase += wt[w];
    int base = part[b] + wbase + wexc;
    int pre = 0;
#pragma unroll
    for (int k = 0; k < 4; ++k) {
        int i = i0 + k;
        if (i < ND) { off[i] = base + pre; cursor[i] = base + pre; }
        pre += v[k];
    }
}

// ---------------------------------------------------------------------------
// Fill: place src ids in CSR order AND precompute the 8 per-head softmax
// numerators w = exp(leaky_relu(a_s + a_d)) for each edge (f16x8, CSR order).
// ---------------------------------------------------------------------------
__global__ __launch_bounds__(256) void fill_kernel(
    const int* __restrict__ ei00, const int* __restrict__ ei10,
    const int* __restrict__ ei11, const int* __restrict__ ei21,
    const float* __restrict__ as00, const float* __restrict__ ad00,
    const float* __restrict__ as10, const float* __restrict__ ad10,
    const float* __restrict__ as11, const float* __restrict__ ad11,
    const float* __restrict__ as21, const float* __restrict__ ad21,
    int* __restrict__ cursor, int* __restrict__ srcs, _Float16* __restrict__ wgt)
{
    int e = blockIdx.x * 256 + threadIdx.x;
    if (e >= EE) return;
    int src, d, slot;
    const float* asp; const float* adp;
    if (e < E00) {
        src = ei00[e]; d = ei00[E00 + e]; slot = d; asp = as00; adp = ad00;
    } else if (e < E00 + E10) {
        int i = e - E00; src = ei10[i]; d = ei10[E10 + i]; slot = 50000 + d; asp = as10; adp = ad10;
    } else if (e < E00 + E10 + E11) {
        int i = e - E00 - E10; src = ei11[i]; d = ei11[E11 + i]; slot = 100000 + d; asp = as11; adp = ad11;
    } else {
        int i = e - E00 - E10 - E11; src = ei21[i]; d = ei21[E21 + i]; slot = 200000 + d; asp = as21; adp = ad21;
    }
    float4 sa0 = *(const float4*)(asp + (size_t)src * 8);
    float4 sa1 = *(const float4*)(asp + (size_t)src * 8 + 4);
    float4 da0 = *(const float4*)(adp + (size_t)d * 8);
    float4 da1 = *(const float4*)(adp + (size_t)d * 8 + 4);
    float vv[8] = {sa0.x + da0.x, sa0.y + da0.y, sa0.z + da0.z, sa0.w + da0.w,
                   sa1.x + da1.x, sa1.y + da1.y, sa1.z + da1.z, sa1.w + da1.w};
    half8 w;
#pragma unroll
    for (int h = 0; h < 8; ++h) {
        float v = vv[h];
        v = v > 0.f ? v : 0.2f * v;
        w[h] = (_Float16)__expf(v);
    }
    int pos = atomicAdd(&cursor[slot], 1);
    srcs[pos] = src;
    *(half8*)(wgt + (size_t)pos * 8) = w;
}

// ---------------------------------------------------------------------------
// Gather: 4 slots per wave, 16 lanes per slot; lane covers 8 fp8 features
// (one b64 load per edge), head = (lane&15)>>1. Weights read sequentially
// from the CSR-ordered wgt array. agg (fp8, relu'ed) written exactly once.
// ---------------------------------------------------------------------------
__global__ __launch_bounds__(256) void gather_kernel(
    const int* __restrict__ cnt, const int* __restrict__ off,
    const int* __restrict__ srcs, const _Float16* __restrict__ wgt,
    const unsigned char* __restrict__ h0, const unsigned char* __restrict__ h1,
    const unsigned char* __restrict__ h2,
    unsigned char* __restrict__ agg)
{
    const int gid = blockIdx.x * 256 + threadIdx.x;
    const int lane = gid & 63;
    const int grp = lane >> 4, lg = lane & 15;
    const int slot = (gid >> 6) * 4 + grp;          // grid sized so slot < ND
    const int head = lg >> 1;
    const unsigned char* hs = (slot < 50000) ? h0 : (slot < 200000) ? h1 : h2;
    const int deg = cnt[slot], st = off[slot];

    int degm = deg;
    degm = max(degm, __shfl_xor(degm, 16));
    degm = max(degm, __shfl_xor(degm, 32));

    float acc[8] = {0.f, 0.f, 0.f, 0.f, 0.f, 0.f, 0.f, 0.f};
    float sw = 0.f;
    int i = 0;
    for (; i + 2 <= degm; i += 2) {
        bool a0 = (i < deg), a1 = (i + 1 < deg);
        int s0 = 0, s1 = 0;
        if (a0) s0 = srcs[st + i];
        if (a1) s1 = srcs[st + i + 1];
        float w0 = 0.f, w1 = 0.f;
        unsigned long long v0 = 0, v1 = 0;
        if (a0) { w0 = (float)wgt[(size_t)(st + i) * 8 + head];
                  v0 = *(const unsigned long long*)(hs + (size_t)s0 * 128 + lg * 8); }
        if (a1) { w1 = (float)wgt[(size_t)(st + i + 1) * 8 + head];
                  v1 = *(const unsigned long long*)(hs + (size_t)s1 * 128 + lg * 8); }
        int l0 = (int)(v0 & 0xffffffffu), m0 = (int)(v0 >> 32);
        int l1 = (int)(v1 & 0xffffffffu), m1 = (int)(v1 >> 32);
        floatx2 f0a = __builtin_amdgcn_cvt_pk_f32_fp8(l0, false);
        floatx2 f0b = __builtin_amdgcn_cvt_pk_f32_fp8(l0, true);
        floatx2 f0c = __builtin_amdgcn_cvt_pk_f32_fp8(m0, false);
        floatx2 f0d = __builtin_amdgcn_cvt_pk_f32_fp8(m0, true);
        floatx2 f1a = __builtin_amdgcn_cvt_pk_f32_fp8(l1, false);
        floatx2 f1b = __builtin_amdgcn_cvt_pk_f32_fp8(l1, true);
        floatx2 f1c = __builtin_amdgcn_cvt_pk_f32_fp8(m1, false);
        floatx2 f1d = __builtin_amdgcn_cvt_pk_f32_fp8(m1, true);
        acc[0] += w0 * f0a.x + w1 * f1a.x;
        acc[1] += w0 * f0a.y + w1 * f1a.y;
        acc[2] += w0 * f0b.x + w1 * f1b.x;
        acc[3] += w0 * f0b.y + w1 * f1b.y;
        acc[4] += w0 * f0c.x + w1 * f1c.x;
        acc[5] += w0 * f0c.y + w1 * f1c.y;
        acc[6] += w0 * f0d.x + w1 * f1d.x;
        acc[7] += w0 * f0d.y + w1 * f1d.y;
        sw += w0 + w1;
    }
    if (i < degm) {
        bool a0 = (i < deg);
        int s0 = 0;
        if (a0) s0 = srcs[st + i];
        float w0 = 0.f;
        unsigned long long v0 = 0;
        if (a0) { w0 = (float)wgt[(size_t)(st + i) * 8 + head];
                  v0 = *(const unsigned long long*)(hs + (size_t)s0 * 128 + lg * 8); }
        int l0 = (int)(v0 & 0xffffffffu), m0 = (int)(v0 >> 32);
        floatx2 f0a = __builtin_amdgcn_cvt_pk_f32_fp8(l0, false);
        floatx2 f0b = __builtin_amdgcn_cvt_pk_f32_fp8(l0, true);
        floatx2 f0c = __builtin_amdgcn_cvt_pk_f32_fp8(m0, false);
        floatx2 f0d = __builtin_amdgcn_cvt_pk_f32_fp8(m0, true);
        acc[0] += w0 * f0a.x; acc[1] += w0 * f0a.y;
        acc[2] += w0 * f0b.x; acc[3] += w0 * f0b.y;
        acc[4] += w0 * f0c.x; acc[5] += w0 * f0c.y;
        acc[6] += w0 * f0d.x; acc[7] += w0 * f0d.y;
        sw += w0;
    }

    float rr = __builtin_amdgcn_rcpf(sw + 1e-16f);
    float r[8];
#pragma unroll
    for (int j = 0; j < 8; ++j) r[j] = fmaxf(acc[j] * rr, 0.f);   // relu here
    int pa = __builtin_amdgcn_cvt_pk_fp8_f32(r[0], r[1], 0, false);
    pa = __builtin_amdgcn_cvt_pk_fp8_f32(r[2], r[3], pa, true);
    int pb = __builtin_amdgcn_cvt_pk_fp8_f32(r[4], r[5], 0, false);
    pb = __builtin_amdgcn_cvt_pk_fp8_f32(r[6], r[7], pb, true);
    int2 o = {pa, pb};
    *(int2*)(agg + (size_t)slot * 128 + lg * 8) = o;
}

// ---------------------------------------------------------------------------
// Stage 4 (fused, fp8 MFMA over all 4 metapaths): Y = agg_relu @ [k_w|lin_w].
// Each wave owns whole tiles (R7 layout). The 9x4 B fragments are loaded from
// LDS ONCE, then kwT is volatile-clobbered behind a barrier so the compiler
// CANNOT re-read them in the loop — they must stay register-resident
// (~140 VGPRs -> 3 waves/SIMD). Next-tile A prefetch hides global latency.
// metapath of tile t: 3=t>=12500, 2=t>=6250, 1=t>=3125, else 0.
// ---------------------------------------------------------------------------
#define KSTRB 136
__global__ __launch_bounds__(256) void semantic_kernel(
    const unsigned char* __restrict__ agg,
    const float* __restrict__ kw, const float* __restrict__ lw,
    const float* __restrict__ kb, const float* __restrict__ q,
    float* __restrict__ cs2, float* __restrict__ score)
{
    __shared__ unsigned char kwT[144 * KSTRB];   // 19.6 KB fp8, f-major
    __shared__ float redv[12];
    const int tid = threadIdx.x;
    const int lane = tid & 63, wv = tid >> 6;
    const int fi = lane & 15, hi = lane >> 4;

    for (int idx = tid; idx < 128 * 128; idx += 256) {
        int g = idx >> 7, f = idx & 127;
        int r = __builtin_amdgcn_cvt_pk_fp8_f32(kw[idx], 0.f, 0, false);
        kwT[f * KSTRB + g] = (unsigned char)r;
    }
    for (int idx = tid; idx < 16 * 128; idx += 256) {
        int f2 = idx >> 7, g = idx & 127;
        float v = (f2 < 2) ? lw[g * 2 + f2] : 0.f;
        int r = __builtin_amdgcn_cvt_pk_fp8_f32(v, 0.f, 0, false);
        kwT[(128 + f2) * KSTRB + g] = (unsigned char)r;
    }
    if (tid < 12) redv[tid] = 0.f;
    __syncthreads();

    long bf[9][4];
#pragma unroll
    for (int ft = 0; ft < 9; ++ft)
#pragma unroll
        for (int kk = 0; kk < 4; ++kk)
            bf[ft][kk] = *(const long*)&kwT[(ft * 16 + fi) * KSTRB + kk * 32 + hi * 8];

    float qv[8], kbv[8];
#pragma unroll
    for (int ft = 0; ft < 8; ++ft) {
        qv[ft] = q[ft * 16 + fi];
        kbv[ft] = kb[ft * 16 + fi];
    }

    // clobber kwT behind a barrier: the fragment ds_reads above can no longer
    // be rematerialized inside the loop -> bf stays in registers.
    __syncthreads();
    ((volatile unsigned char*)kwT)[tid] = 0;

    float sc[4] = {0.f, 0.f, 0.f, 0.f};
    float cs[4] = {0.f, 0.f, 0.f, 0.f};
    const int wid = blockIdx.x * 4 + wv;
    const int nw = gridDim.x * 4;

    long af[4] = {0, 0, 0, 0};
    int t = wid;
    if (t < NT_ALL) {
        const unsigned char* rowp = agg + ((size_t)(t * 16 + fi) * 128 + hi * 8);
        af[0] = *(const long*)(rowp);
        af[1] = *(const long*)(rowp + 32);
        af[2] = *(const long*)(rowp + 64);
        af[3] = *(const long*)(rowp + 96);
    }
    while (t < NT_ALL) {
        const int tn = t + nw;
        long afn[4] = {0, 0, 0, 0};
        if (tn < NT_ALL) {
            const unsigned char* rowp = agg + ((size_t)(tn * 16 + fi) * 128 + hi * 8);
            afn[0] = *(const long*)(rowp);
            afn[1] = *(const long*)(rowp + 32);
            afn[2] = *(const long*)(rowp + 64);
            afn[3] = *(const long*)(rowp + 96);
        }
        const int m = (t >= 12500) ? 3 : (t >= 6250) ? 2 : (t >= 3125) ? 1 : 0;
        float tsc = 0.f, tcs;
#pragma unroll
        for (int ft = 0; ft < 8; ++ft) {
            float4v c = {0.f, 0.f, 0.f, 0.f};
            c = __builtin_amdgcn_mfma_f32_16x16x32_fp8_fp8(af[0], bf[ft][0], c, 0, 0, 0);
            c = __builtin_amdgcn_mfma_f32_16x16x32_fp8_fp8(af[1], bf[ft][1], c, 0, 0, 0);
            c = __builtin_amdgcn_mfma_f32_16x16x32_fp8_fp8(af[2], bf[ft][2], c, 0, 0, 0);
            c = __builtin_amdgcn_mfma_f32_16x16x32_fp8_fp8(af[3], bf[ft][3], c, 0, 0, 0);
#pragma unroll
            for (int r = 0; r < 4; ++r) {
                float y = c[r] + kbv[ft];
                float e = __expf(2.f * y);
                tsc += qv[ft] * (1.f - 2.f * __builtin_amdgcn_rcpf(e + 1.f));
            }
        }
        {
            float4v c = {0.f, 0.f, 0.f, 0.f};
            c = __builtin_amdgcn_mfma_f32_16x16x32_fp8_fp8(af[0], bf[8][0], c, 0, 0, 0);
            c = __builtin_amdgcn_mfma_f32_16x16x32_fp8_fp8(af[1], bf[8][1], c, 0, 0, 0);
            c = __builtin_amdgcn_mfma_f32_16x16x32_fp8_fp8(af[2], bf[8][2], c, 0, 0, 0);
            c = __builtin_amdgcn_mfma_f32_16x16x32_fp8_fp8(af[3], bf[8][3], c, 0, 0, 0);
            tcs = c[0] + c[1] + c[2] + c[3];
        }
        if (m == 0)      { sc[0] += tsc; cs[0] += tcs; }
        else if (m == 1) { sc[1] += tsc; cs[1] += tcs; }
        else if (m == 2) { sc[2] += tsc; cs[2] += tcs; }
        else             { sc[3] += tsc; cs[3] += tcs; }
        t = tn;
        af[0] = afn[0]; af[1] = afn[1]; af[2] = afn[2]; af[3] = afn[3];
    }

#pragma unroll
    for (int m = 0; m < 4; ++m) {
        float s = sc[m];
#pragma unroll
        for (int off = 1; off < 64; off <<= 1) s += __shfl_xor(s, off);
        if (lane == 0 && s != 0.f) atomicAdd(&redv[m], s);
        float v = cs[m];
        v += __shfl_xor(v, 16);
        v += __shfl_xor(v, 32);
        if (hi == 0 && fi < 2 && v != 0.f) atomicAdd(&redv[4 + 2 * m + fi], v);
    }
    __syncthreads();
    if (tid < 4)              atomicAdd(&score[tid], redv[tid]);
    if (tid >= 4 && tid < 12) atomicAdd(&cs2[tid - 4], redv[tid]);
}

// ---------------------------------------------------------------------------
// Stage 5: semantic softmax + classifier + sigmoid. One thread.
// ---------------------------------------------------------------------------
__global__ void final_kernel(const float* __restrict__ cs2,
                             const float* __restrict__ score,
                             const float* __restrict__ lb,
                             float* __restrict__ out)
{
    float s0 = score[0] / (float)N0;
    float s1 = score[1] / (float)N0;
    float s2 = score[2] / (float)N1;
    float s3 = score[3] / (float)N1;
    float m0 = fmaxf(s0, s1);
    float e0 = expf(s0 - m0), e1 = expf(s1 - m0);
    float a0 = e0 / (e0 + e1), a1 = e1 / (e0 + e1);
    float m1 = fmaxf(s2, s3);
    float e2 = expf(s2 - m1), e3 = expf(s3 - m1);
    float a2 = e2 / (e2 + e3), a3 = e3 / (e2 + e3);
    float z0 = a0 * cs2[0] + a1 * cs2[2] + a2 * cs2[4] + a3 * cs2[6] + lb[0];
    float z1 = a0 * cs2[1] + a1 * cs2[3] + a2 * cs2[5] + a3 * cs2[7] + lb[1];
    out[0] = 1.f / (1.f + expf(-z0));
    out[1] = 1.f / (1.f + expf(-z1));
}

extern "C" void kernel_launch(void* const* d_in, const int* in_sizes, int n_in,
                              void* d_out, int out_size, void* d_ws, size_t ws_size,
                              hipStream_t stream)
{
    const float* x0  = (const float*)d_in[0];
    const float* x1  = (const float*)d_in[1];
    const float* x2  = (const float*)d_in[2];
    const int* ei00  = (const int*)d_in[3];
    const int* ei11  = (const int*)d_in[4];
    const int* ei10  = (const int*)d_in[5];
    const int* ei21  = (const int*)d_in[6];
    const float* W0  = (const float*)d_in[7];  const float* b0 = (const float*)d_in[8];
    const float* W1  = (const float*)d_in[9];  const float* b1 = (const float*)d_in[10];
    const float* W2  = (const float*)d_in[11]; const float* b2 = (const float*)d_in[12];
    const float* as00 = (const float*)d_in[13]; const float* ad00 = (const float*)d_in[14];
    const float* as11 = (const float*)d_in[15]; const float* ad11 = (const float*)d_in[16];
    const float* as10 = (const float*)d_in[17]; const float* ad10 = (const float*)d_in[18];
    const float* as21 = (const float*)d_in[19]; const float* ad21 = (const float*)d_in[20];
    const float* kw  = (const float*)d_in[21]; const float* kb  = (const float*)d_in[22];
    const float* q   = (const float*)d_in[23];
    const float* lw  = (const float*)d_in[24]; const float* lb  = (const float*)d_in[25];
    float* out = (float*)d_out;

    char* p = (char*)d_ws;
    auto alloc = [&](size_t bytes) {
        char* r = p;
        p += (bytes + 255) & ~(size_t)255;
        return r;
    };
    unsigned char* h0 = (unsigned char*)alloc((size_t)N0 * 128);   // fp8 [N][128]
    unsigned char* h1 = (unsigned char*)alloc((size_t)N1 * 128);
    unsigned char* h2 = (unsigned char*)alloc((size_t)N2 * 128);
    float* o_as00 = (float*)alloc((size_t)N0 * 32);
    float* o_ad00 = (float*)alloc((size_t)N0 * 32);
    float* o_as11 = (float*)alloc((size_t)N1 * 32);
    float* o_ad11 = (float*)alloc((size_t)N1 * 32);
    float* o_as10 = (float*)alloc((size_t)N1 * 32);   // src of b10 = cell1
    float* o_ad10 = (float*)alloc((size_t)N0 * 32);   // dst of b10 = cell0
    float* o_as21 = (float*)alloc((size_t)N2 * 32);   // src of b21 = cell2
    float* o_ad21 = (float*)alloc((size_t)N1 * 32);   // dst of b21 = cell1
    int* off    = (int*)alloc((size_t)ND * 4);
    int* cursor = (int*)alloc((size_t)ND * 4);
    int* part   = (int*)alloc((size_t)512 * 4);
    int* srcs   = (int*)alloc((size_t)EE * 4);
    _Float16* wgt = (_Float16*)alloc((size_t)EE * 16);             // f16x8 per edge
    unsigned char* agg = (unsigned char*)alloc((size_t)ND * 128);  // fp8 [u00|b10|u11|b21]
    // ---- zero region (contiguous) ----
    char* zstart = p;
    int* cnt = (int*)alloc((size_t)ND * 4);
    float* colsum2 = (float*)alloc(8 * 4);
    float* score   = (float*)alloc(4 * 4);
    size_t zbytes = (size_t)(p - zstart);

    (void)hipMemsetAsync(zstart, 0, zbytes, stream);

    // fused MFMA projection: blocks [0,296) cell0, [296,880) cell1, [880,1024) cell2
    PT t0 = {x0, W0, b0, h0,
             as00, ad00, ad10, nullptr,
             o_as00, o_ad00, o_ad10, nullptr,
             N0, 3125, 0, 296};
    PT t1 = {x1, W1, b1, h1,
             as11, ad11, as10, ad21,
             o_as11, o_ad11, o_as10, o_ad21,
             N1, 6250, 296, 584};
    PT t2 = {x2, W2, b2, h2,
             as21, nullptr, nullptr, nullptr,
             o_as21, nullptr, nullptr, nullptr,
             N2, 1563, 880, 144};
    proj_mfma<<<1024, 256, 0, stream>>>(t0, t1, t2);

    // CSR build
    count_kernel<<<(EE + 255) / 256, 256, 0, stream>>>(ei00, ei10, ei11, ei21, cnt);
    scan1_kernel<<<NB, 256, 0, stream>>>(cnt, part);
    scan2_kernel<<<1, 256, 0, stream>>>(part);
    scan3_kernel<<<NB, 256, 0, stream>>>(cnt, part, off, cursor);
    fill_kernel<<<(EE + 255) / 256, 256, 0, stream>>>(ei00, ei10, ei11, ei21,
        o_as00, o_ad00, o_as10, o_ad10, o_as11, o_ad11, o_as21, o_ad21,
        cursor, srcs, wgt);

    // gather (4 slots/wave, CSR-ordered weights, fp8 h rows)
    gather_kernel<<<ND / 16, 256, 0, stream>>>(cnt, off, srcs, wgt, h0, h1, h2, agg);

    // fused semantic reduction over all 4 metapaths (fp8 MFMA, register-pinned B)
    semantic_kernel<<<768, 256, 0, stream>>>(agg, kw, lw, kb, q, colsum2, score);

    final_kernel<<<1, 1, 0, stream>>>(colsum2, score, lb, out);
}

// Round 10
// 295.683 us; speedup vs baseline: 1.1593x; 1.0668x over previous
//
#include <hip/hip_runtime.h>
#include <hip/hip_fp16.h>

#define N0 50000
#define N1 100000
#define N2 25000
#define E00 200000
#define E11 200000
#define E10 100000
#define E21 50000
#define EE  550000   // E00+E10+E11+E21 (concatenated edge space)
#define ND  300000   // 50000(u00)+50000(b10)+100000(u11)+100000(b21) dst slots
#define NB  293      // ceil(ND/1024) scan blocks
#define NT_ALL 18750 // ND/16 semantic tiles
#define HID 128
#define INC 64

typedef _Float16 half8 __attribute__((ext_vector_type(8)));
typedef _Float16 half4_t __attribute__((ext_vector_type(4)));
typedef float float4v __attribute__((ext_vector_type(4)));
typedef float floatx2 __attribute__((ext_vector_type(2)));

// ---------------------------------------------------------------------------
// Stage 0 (prep): per node type, write to GLOBAL (f16, L2/L3-resident):
//   wtg[f][g]  = W[g][f]                  (128 x 64)  — MFMA B for h
//   adtg[c][g] = (W·A)^T[c][g]            (32 x 64)   — MFMA B for attn dots
//   bdc[c]     = sum_d bias[hh*16+d]*av[hh*16+d]      (32 scalars)
// This removes all per-block W staging / transpose / AdT-build LDS traffic
// (8.8M bank-conflict cycles in R9) from proj_mfma.
// ---------------------------------------------------------------------------
struct PrepT {
    const float* W; const float* bias;
    const float* av0; const float* av1; const float* av2; const float* av3;
    _Float16* wtg; _Float16* adtg; float* bdc;
};

__global__ __launch_bounds__(256) void prep_kernel(PrepT p0, PrepT p1, PrepT p2)
{
    PrepT P = (blockIdx.x >= 16) ? p2 : (blockIdx.x >= 8) ? p1 : p0;
    const int lb = blockIdx.x & 7;
    const int t2 = lb * 256 + threadIdx.x;   // 0..2047

    // transpose W -> wtg (thread: fixed f, 4 consecutive g, b64 write)
    {
        int f = t2 >> 4, g0 = (t2 & 15) * 4;
        half4_t v;
#pragma unroll
        for (int j = 0; j < 4; ++j) v[j] = (_Float16)P.W[(g0 + j) * 128 + f];
        *(half4_t*)&P.wtg[f * 64 + g0] = v;
    }
    // (W·A)^T -> adtg (thread: one (c,g) output, 16 contiguous W reads)
    {
        int c = t2 >> 6, g = t2 & 63;
        const float* av = (c < 8) ? P.av0 : (c < 16) ? P.av1 : (c < 24) ? P.av2 : P.av3;
        float v = 0.f;
        if (av) {
            int hh = c & 7;
#pragma unroll
            for (int d = 0; d < 16; ++d)
                v += P.W[g * 128 + hh * 16 + d] * av[hh * 16 + d];
        }
        P.adtg[c * 64 + g] = (_Float16)v;
    }
    // bdc
    if (lb == 0 && threadIdx.x < 32) {
        int c = threadIdx.x;
        const float* av = (c < 8) ? P.av0 : (c < 16) ? P.av1 : (c < 24) ? P.av2 : P.av3;
        float v = 0.f;
        if (av) {
            int hh = c & 7;
#pragma unroll
            for (int d = 0; d < 16; ++d)
                v += P.bias[hh * 16 + d] * av[hh * 16 + d];
        }
        P.bdc[c] = v;
    }
}

// ---------------------------------------------------------------------------
// Stage 1 (fused, MFMA): per node type, h = x @ W + b (fp8 e4m3, [N][128] B)
// and attention dots (fp32 [N][8]). B fragments loaded ONCE from global
// prep buffers (no W LDS at all). __launch_bounds__(256,2) -> 256-VGPR
// budget so the 20 fragments stay register-resident.
// mfma_f32_16x16x32_f16: A[m=lane&15][k=(lane>>4)*8+j]; B[k][n=lane&15];
// C: col=lane&15, row=(lane>>4)*4+reg.
// ---------------------------------------------------------------------------
struct PT {
    const float* x; const float* bias; unsigned char* h;
    float* ao0; float* ao1; float* ao2; float* ao3;
    const _Float16* wtg; const _Float16* adtg; const float* bdc;
    int N; int ntiles; int bstart; int nblocks;
};

#define HPAD 136  // halves; row stride 272 B (16B-aligned b128 reads)

__global__ __launch_bounds__(256, 2) void proj_mfma(PT t0, PT t1, PT t2)
{
    __shared__ _Float16 ht[4][16][HPAD];   // 17.4 KB: per-wave h tile (f16)
    const int tid = threadIdx.x;
    const int lane = tid & 63, wv = tid >> 6;
    const int fi = lane & 15, hi = lane >> 4;

    PT A = (blockIdx.x >= t2.bstart) ? t2 : (blockIdx.x >= t1.bstart) ? t1 : t0;

    // persistent B fragments straight from global (16 B/lane each, L2-hit)
    half8 bfr[8][2], bd[2][2];
#pragma unroll
    for (int nt = 0; nt < 8; ++nt)
#pragma unroll
        for (int kb = 0; kb < 2; ++kb)
            bfr[nt][kb] = *(const half8*)&A.wtg[(nt * 16 + fi) * 64 + kb * 32 + hi * 8];
#pragma unroll
    for (int t = 0; t < 2; ++t)
#pragma unroll
        for (int kb = 0; kb < 2; ++kb)
            bd[t][kb] = *(const half8*)&A.adtg[(t * 16 + fi) * 64 + kb * 32 + hi * 8];

    float bvv[8];
#pragma unroll
    for (int nt = 0; nt < 8; ++nt) bvv[nt] = A.bias[nt * 16 + fi];
    const float bdc0 = A.bdc[fi];
    const float bdc1 = A.bdc[16 + fi];

    float* aolo = (fi >= 8) ? A.ao1 : A.ao0;
    float* aohi = (fi >= 8) ? A.ao3 : A.ao2;
    const bool has_hi = (A.ao2 != nullptr) || (A.ao3 != nullptr);

    const int stride = A.nblocks * 4;
    for (int t = (blockIdx.x - A.bstart) * 4 + wv; t < A.ntiles; t += stride) {
        const int base = t * 16;
        int rsrc = base + fi; if (rsrc >= A.N) rsrc = A.N - 1;
        const float* xp = A.x + (size_t)rsrc * 64 + hi * 8;
        float4 u0 = *(const float4*)(xp);
        float4 u1 = *(const float4*)(xp + 4);
        float4 u2 = *(const float4*)(xp + 32);
        float4 u3 = *(const float4*)(xp + 36);
        half8 a0, a1;
        a0[0] = (_Float16)u0.x; a0[1] = (_Float16)u0.y; a0[2] = (_Float16)u0.z; a0[3] = (_Float16)u0.w;
        a0[4] = (_Float16)u1.x; a0[5] = (_Float16)u1.y; a0[6] = (_Float16)u1.z; a0[7] = (_Float16)u1.w;
        a1[0] = (_Float16)u2.x; a1[1] = (_Float16)u2.y; a1[2] = (_Float16)u2.z; a1[3] = (_Float16)u2.w;
        a1[4] = (_Float16)u3.x; a1[5] = (_Float16)u3.y; a1[6] = (_Float16)u3.z; a1[7] = (_Float16)u3.w;

        float4v c[8];
#pragma unroll
        for (int nt = 0; nt < 8; ++nt) {
            float4v z = {0.f, 0.f, 0.f, 0.f};
            z = __builtin_amdgcn_mfma_f32_16x16x32_f16(a0, bfr[nt][0], z, 0, 0, 0);
            z = __builtin_amdgcn_mfma_f32_16x16x32_f16(a1, bfr[nt][1], z, 0, 0, 0);
            c[nt] = z;
        }
        float4v d0 = {0.f, 0.f, 0.f, 0.f};
        d0 = __builtin_amdgcn_mfma_f32_16x16x32_f16(a0, bd[0][0], d0, 0, 0, 0);
        d0 = __builtin_amdgcn_mfma_f32_16x16x32_f16(a1, bd[0][1], d0, 0, 0, 0);
        float4v d1 = {0.f, 0.f, 0.f, 0.f};
        if (has_hi) {
            d1 = __builtin_amdgcn_mfma_f32_16x16x32_f16(a0, bd[1][0], d1, 0, 0, 0);
            d1 = __builtin_amdgcn_mfma_f32_16x16x32_f16(a1, bd[1][1], d1, 0, 0, 0);
        }

        // h epilogue: C frags -> per-wave LDS tile -> fp8 coalesced stores
#pragma unroll
        for (int nt = 0; nt < 8; ++nt)
#pragma unroll
            for (int r = 0; r < 4; ++r)
                ht[wv][hi * 4 + r][nt * 16 + fi] = (_Float16)(c[nt][r] + bvv[nt]);
#pragma unroll
        for (int i = 0; i < 4; ++i) {
            int row = i * 4 + hi;
            int node = base + row;
            if (node < A.N) {
                half8 v = *(const half8*)&ht[wv][row][fi * 8];
                int pa = __builtin_amdgcn_cvt_pk_fp8_f32((float)v[0], (float)v[1], 0, false);
                pa = __builtin_amdgcn_cvt_pk_fp8_f32((float)v[2], (float)v[3], pa, true);
                int pb = __builtin_amdgcn_cvt_pk_fp8_f32((float)v[4], (float)v[5], 0, false);
                pb = __builtin_amdgcn_cvt_pk_fp8_f32((float)v[6], (float)v[7], pb, true);
                int2 o = {pa, pb};
                *(int2*)(A.h + (size_t)node * 128 + fi * 8) = o;
            }
        }
        if (aolo) {
#pragma unroll
            for (int r = 0; r < 4; ++r) {
                int node = base + hi * 4 + r;
                if (node < A.N) aolo[(size_t)node * 8 + (fi & 7)] = d0[r] + bdc0;
            }
        }
        if (aohi) {
#pragma unroll
            for (int r = 0; r < 4; ++r) {
                int node = base + hi * 4 + r;
                if (node < A.N) aohi[(size_t)node * 8 + (fi & 7)] = d1[r] + bdc1;
            }
        }
    }
}

// ---------------------------------------------------------------------------
// CSR build over the concatenated (edge-type, dst) slot space.
// ---------------------------------------------------------------------------
__device__ __forceinline__ void decode_edge(
    int e, const int* ei00, const int* ei10, const int* ei11, const int* ei21,
    int& src, int& slot)
{
    if (e < E00)                    { src = ei00[e];               slot = ei00[E00 + e]; }
    else if (e < E00 + E10)         { int i = e - E00;             src = ei10[i]; slot = 50000  + ei10[E10 + i]; }
    else if (e < E00 + E10 + E11)   { int i = e - E00 - E10;       src = ei11[i]; slot = 100000 + ei11[E11 + i]; }
    else                            { int i = e - E00 - E10 - E11; src = ei21[i]; slot = 200000 + ei21[E21 + i]; }
}

__global__ __launch_bounds__(256) void count_kernel(
    const int* __restrict__ ei00, const int* __restrict__ ei10,
    const int* __restrict__ ei11, const int* __restrict__ ei21,
    int* __restrict__ cnt)
{
    int e = blockIdx.x * 256 + threadIdx.x;
    if (e >= EE) return;
    int src, slot;
    decode_edge(e, ei00, ei10, ei11, ei21, src, slot);
    atomicAdd(&cnt[slot], 1);
}

__global__ __launch_bounds__(256) void scan1_kernel(
    const int* __restrict__ cnt, int* __restrict__ part)
{
    const int tid = threadIdx.x, b = blockIdx.x;
    int i0 = b * 1024 + tid * 4;
    int s = 0;
#pragma unroll
    for (int k = 0; k < 4; ++k) { int i = i0 + k; s += (i < ND) ? cnt[i] : 0; }
#pragma unroll
    for (int off = 1; off < 64; off <<= 1) s += __shfl_xor(s, off);
    __shared__ int wt[4];
    if ((tid & 63) == 0) wt[tid >> 6] = s;
    __syncthreads();
    if (tid == 0) part[b] = wt[0] + wt[1] + wt[2] + wt[3];
}

__global__ __launch_bounds__(256) void scan2_kernel(int* __restrict__ part)
{
    const int t = threadIdx.x;
    int p0 = (2 * t     < NB) ? part[2 * t]     : 0;
    int p1 = (2 * t + 1 < NB) ? part[2 * t + 1] : 0;
    int ps = p0 + p1;
    __shared__ int sd[256];
    sd[t] = ps; __syncthreads();
    for (int d = 1; d < 256; d <<= 1) {
        int v = (t >= d) ? sd[t - d] : 0;
        __syncthreads();
        sd[t] += v;
        __syncthreads();
    }
    int exc = sd[t] - ps;
    if (2 * t     < NB) part[2 * t]     = exc;
    if (2 * t + 1 < NB) part[2 * t + 1] = exc + p0;
}

__global__ __launch_bounds__(256) void scan3_kernel(
    const int* __restrict__ cnt, const int* __restrict__ part,
    int* __restrict__ off, int* __restrict__ cursor)
{
    const int tid = threadIdx.x, b = blockIdx.x;
    const int lane = tid & 63, wv = tid >> 6;
    int i0 = b * 1024 + tid * 4;
    int v[4];
#pragma unroll
    for (int k = 0; k < 4; ++k) { int i = i0 + k; v[k] = (i < ND) ? cnt[i] : 0; }
    int ts = v[0] + v[1] + v[2] + v[3];
    int inc = ts;
#pragma unroll
    for (int d = 1; d < 64; d <<= 1) {
        int u = __shfl_up(inc, d);
        if (lane >= d) inc += u;
    }
    int wexc = inc - ts;
    __shared__ int wt[4];
    if (lane == 63) wt[wv] = inc;
    __syncthreads();
    int wbase = 0;
    for (int w = 0; w < wv; ++w) wbase += wt[w];
    int base = part[b] + wbase + wexc;
    int pre = 0;
#pragma unroll
    for (int k = 0; k < 4; ++k) {
        int i = i0 + k;
        if (i < ND) { off[i] = base + pre; cursor[i] = base + pre; }
        pre += v[k];
    }
}

// ---------------------------------------------------------------------------
// Fill: place src ids in CSR order AND precompute the 8 per-head softmax
// numerators w = exp(leaky_relu(a_s + a_d)) for each edge (f16x8, CSR order).
// ---------------------------------------------------------------------------
__global__ __launch_bounds__(256) void fill_kernel(
    const int* __restrict__ ei00, const int* __restrict__ ei10,
    const int* __restrict__ ei11, const int* __restrict__ ei21,
    const float* __restrict__ as00, const float* __restrict__ ad00,
    const float* __restrict__ as10, const float* __restrict__ ad10,
    const float* __restrict__ as11, const float* __restrict__ ad11,
    const float* __restrict__ as21, const float* __restrict__ ad21,
    int* __restrict__ cursor, int* __restrict__ srcs, _Float16* __restrict__ wgt)
{
    int e = blockIdx.x * 256 + threadIdx.x;
    if (e >= EE) return;
    int src, d, slot;
    const float* asp; const float* adp;
    if (e < E00) {
        src = ei00[e]; d = ei00[E00 + e]; slot = d; asp = as00; adp = ad00;
    } else if (e < E00 + E10) {
        int i = e - E00; src = ei10[i]; d = ei10[E10 + i]; slot = 50000 + d; asp = as10; adp = ad10;
    } else if (e < E00 + E10 + E11) {
        int i = e - E00 - E10; src = ei11[i]; d = ei11[E11 + i]; slot = 100000 + d; asp = as11; adp = ad11;
    } else {
        int i = e - E00 - E10 - E11; src = ei21[i]; d = ei21[E21 + i]; slot = 200000 + d; asp = as21; adp = ad21;
    }
    float4 sa0 = *(const float4*)(asp + (size_t)src * 8);
    float4 sa1 = *(const float4*)(asp + (size_t)src * 8 + 4);
    float4 da0 = *(const float4*)(adp + (size_t)d * 8);
    float4 da1 = *(const float4*)(adp + (size_t)d * 8 + 4);
    float vv[8] = {sa0.x + da0.x, sa0.y + da0.y, sa0.z + da0.z, sa0.w + da0.w,
                   sa1.x + da1.x, sa1.y + da1.y, sa1.z + da1.z, sa1.w + da1.w};
    half8 w;
#pragma unroll
    for (int h = 0; h < 8; ++h) {
        float v = vv[h];
        v = v > 0.f ? v : 0.2f * v;
        w[h] = (_Float16)__expf(v);
    }
    int pos = atomicAdd(&cursor[slot], 1);
    srcs[pos] = src;
    *(half8*)(wgt + (size_t)pos * 8) = w;
}

// ---------------------------------------------------------------------------
// Gather: 4 slots per wave, 16 lanes per slot; lane covers 8 fp8 features
// (one b64 load per edge), head = (lane&15)>>1. Weights read sequentially
// from the CSR-ordered wgt array. agg (fp8, relu'ed) written exactly once.
// ---------------------------------------------------------------------------
__global__ __launch_bounds__(256) void gather_kernel(
    const int* __restrict__ cnt, const int* __restrict__ off,
    const int* __restrict__ srcs, const _Float16* __restrict__ wgt,
    const unsigned char* __restrict__ h0, const unsigned char* __restrict__ h1,
    const unsigned char* __restrict__ h2,
    unsigned char* __restrict__ agg)
{
    const int gid = blockIdx.x * 256 + threadIdx.x;
    const int lane = gid & 63;
    const int grp = lane >> 4, lg = lane & 15;
    const int slot = (gid >> 6) * 4 + grp;          // grid sized so slot < ND
    const int head = lg >> 1;
    const unsigned char* hs = (slot < 50000) ? h0 : (slot < 200000) ? h1 : h2;
    const int deg = cnt[slot], st = off[slot];

    int degm = deg;
    degm = max(degm, __shfl_xor(degm, 16));
    degm = max(degm, __shfl_xor(degm, 32));

    float acc[8] = {0.f, 0.f, 0.f, 0.f, 0.f, 0.f, 0.f, 0.f};
    float sw = 0.f;
    int i = 0;
    for (; i + 2 <= degm; i += 2) {
        bool a0 = (i < deg), a1 = (i + 1 < deg);
        int s0 = 0, s1 = 0;
        if (a0) s0 = srcs[st + i];
        if (a1) s1 = srcs[st + i + 1];
        float w0 = 0.f, w1 = 0.f;
        unsigned long long v0 = 0, v1 = 0;
        if (a0) { w0 = (float)wgt[(size_t)(st + i) * 8 + head];
                  v0 = *(const unsigned long long*)(hs + (size_t)s0 * 128 + lg * 8); }
        if (a1) { w1 = (float)wgt[(size_t)(st + i + 1) * 8 + head];
                  v1 = *(const unsigned long long*)(hs + (size_t)s1 * 128 + lg * 8); }
        int l0 = (int)(v0 & 0xffffffffu), m0 = (int)(v0 >> 32);
        int l1 = (int)(v1 & 0xffffffffu), m1 = (int)(v1 >> 32);
        floatx2 f0a = __builtin_amdgcn_cvt_pk_f32_fp8(l0, false);
        floatx2 f0b = __builtin_amdgcn_cvt_pk_f32_fp8(l0, true);
        floatx2 f0c = __builtin_amdgcn_cvt_pk_f32_fp8(m0, false);
        floatx2 f0d = __builtin_amdgcn_cvt_pk_f32_fp8(m0, true);
        floatx2 f1a = __builtin_amdgcn_cvt_pk_f32_fp8(l1, false);
        floatx2 f1b = __builtin_amdgcn_cvt_pk_f32_fp8(l1, true);
        floatx2 f1c = __builtin_amdgcn_cvt_pk_f32_fp8(m1, false);
        floatx2 f1d = __builtin_amdgcn_cvt_pk_f32_fp8(m1, true);
        acc[0] += w0 * f0a.x + w1 * f1a.x;
        acc[1] += w0 * f0a.y + w1 * f1a.y;
        acc[2] += w0 * f0b.x + w1 * f1b.x;
        acc[3] += w0 * f0b.y + w1 * f1b.y;
        acc[4] += w0 * f0c.x + w1 * f1c.x;
        acc[5] += w0 * f0c.y + w1 * f1c.y;
        acc[6] += w0 * f0d.x + w1 * f1d.x;
        acc[7] += w0 * f0d.y + w1 * f1d.y;
        sw += w0 + w1;
    }
    if (i < degm) {
        bool a0 = (i < deg);
        int s0 = 0;
        if (a0) s0 = srcs[st + i];
        float w0 = 0.f;
        unsigned long long v0 = 0;
        if (a0) { w0 = (float)wgt[(size_t)(st + i) * 8 + head];
                  v0 = *(const unsigned long long*)(hs + (size_t)s0 * 128 + lg * 8); }
        int l0 = (int)(v0 & 0xffffffffu), m0 = (int)(v0 >> 32);
        floatx2 f0a = __builtin_amdgcn_cvt_pk_f32_fp8(l0, false);
        floatx2 f0b = __builtin_amdgcn_cvt_pk_f32_fp8(l0, true);
        floatx2 f0c = __builtin_amdgcn_cvt_pk_f32_fp8(m0, false);
        floatx2 f0d = __builtin_amdgcn_cvt_pk_f32_fp8(m0, true);
        acc[0] += w0 * f0a.x; acc[1] += w0 * f0a.y;
        acc[2] += w0 * f0b.x; acc[3] += w0 * f0b.y;
        acc[4] += w0 * f0c.x; acc[5] += w0 * f0c.y;
        acc[6] += w0 * f0d.x; acc[7] += w0 * f0d.y;
        sw += w0;
    }

    float rr = __builtin_amdgcn_rcpf(sw + 1e-16f);
    float r[8];
#pragma unroll
    for (int j = 0; j < 8; ++j) r[j] = fmaxf(acc[j] * rr, 0.f);   // relu here
    int pa = __builtin_amdgcn_cvt_pk_fp8_f32(r[0], r[1], 0, false);
    pa = __builtin_amdgcn_cvt_pk_fp8_f32(r[2], r[3], pa, true);
    int pb = __builtin_amdgcn_cvt_pk_fp8_f32(r[4], r[5], 0, false);
    pb = __builtin_amdgcn_cvt_pk_fp8_f32(r[6], r[7], pb, true);
    int2 o = {pa, pb};
    *(int2*)(agg + (size_t)slot * 128 + lg * 8) = o;
}

// ---------------------------------------------------------------------------
// Stage 4 (fused, fp8 MFMA over all 4 metapaths): Y = agg_relu @ [k_w|lin_w].
// B fragments loaded from LDS once, then kwT volatile-clobbered behind a
// barrier so they must stay register-resident. Next-tile A prefetch.
// metapath of tile t: 3=t>=12500, 2=t>=6250, 1=t>=3125, else 0.
// ---------------------------------------------------------------------------
#define KSTRB 136
__global__ __launch_bounds__(256) void semantic_kernel(
    const unsigned char* __restrict__ agg,
    const float* __restrict__ kw, const float* __restrict__ lw,
    const float* __restrict__ kb, const float* __restrict__ q,
    float* __restrict__ cs2, float* __restrict__ score)
{
    __shared__ unsigned char kwT[144 * KSTRB];   // 19.6 KB fp8, f-major
    __shared__ float redv[12];
    const int tid = threadIdx.x;
    const int lane = tid & 63, wv = tid >> 6;
    const int fi = lane & 15, hi = lane >> 4;

    for (int idx = tid; idx < 128 * 128; idx += 256) {
        int g = idx >> 7, f = idx & 127;
        int r = __builtin_amdgcn_cvt_pk_fp8_f32(kw[idx], 0.f, 0, false);
        kwT[f * KSTRB + g] = (unsigned char)r;
    }
    for (int idx = tid; idx < 16 * 128; idx += 256) {
        int f2 = idx >> 7, g = idx & 127;
        float v = (f2 < 2) ? lw[g * 2 + f2] : 0.f;
        int r = __builtin_amdgcn_cvt_pk_fp8_f32(v, 0.f, 0, false);
        kwT[(128 + f2) * KSTRB + g] = (unsigned char)r;
    }
    if (tid < 12) redv[tid] = 0.f;
    __syncthreads();

    long bf[9][4];
#pragma unroll
    for (int ft = 0; ft < 9; ++ft)
#pragma unroll
        for (int kk = 0; kk < 4; ++kk)
            bf[ft][kk] = *(const long*)&kwT[(ft * 16 + fi) * KSTRB + kk * 32 + hi * 8];

    float qv[8], kbv[8];
#pragma unroll
    for (int ft = 0; ft < 8; ++ft) {
        qv[ft] = q[ft * 16 + fi];
        kbv[ft] = kb[ft * 16 + fi];
    }

    // clobber kwT behind a barrier: the fragment ds_reads above can no longer
    // be rematerialized inside the loop -> bf stays in registers.
    __syncthreads();
    ((volatile unsigned char*)kwT)[tid] = 0;

    float sc[4] = {0.f, 0.f, 0.f, 0.f};
    float cs[4] = {0.f, 0.f, 0.f, 0.f};
    const int wid = blockIdx.x * 4 + wv;
    const int nw = gridDim.x * 4;

    long af[4] = {0, 0, 0, 0};
    int t = wid;
    if (t < NT_ALL) {
        const unsigned char* rowp = agg + ((size_t)(t * 16 + fi) * 128 + hi * 8);
        af[0] = *(const long*)(rowp);
        af[1] = *(const long*)(rowp + 32);
        af[2] = *(const long*)(rowp + 64);
        af[3] = *(const long*)(rowp + 96);
    }
    while (t < NT_ALL) {
        const int tn = t + nw;
        long afn[4] = {0, 0, 0, 0};
        if (tn < NT_ALL) {
            const unsigned char* rowp = agg + ((size_t)(tn * 16 + fi) * 128 + hi * 8);
            afn[0] = *(const long*)(rowp);
            afn[1] = *(const long*)(rowp + 32);
            afn[2] = *(const long*)(rowp + 64);
            afn[3] = *(const long*)(rowp + 96);
        }
        const int m = (t >= 12500) ? 3 : (t >= 6250) ? 2 : (t >= 3125) ? 1 : 0;
        float tsc = 0.f, tcs;
#pragma unroll
        for (int ft = 0; ft < 8; ++ft) {
            float4v c = {0.f, 0.f, 0.f, 0.f};
            c = __builtin_amdgcn_mfma_f32_16x16x32_fp8_fp8(af[0], bf[ft][0], c, 0, 0, 0);
            c = __builtin_amdgcn_mfma_f32_16x16x32_fp8_fp8(af[1], bf[ft][1], c, 0, 0, 0);
            c = __builtin_amdgcn_mfma_f32_16x16x32_fp8_fp8(af[2], bf[ft][2], c, 0, 0, 0);
            c = __builtin_amdgcn_mfma_f32_16x16x32_fp8_fp8(af[3], bf[ft][3], c, 0, 0, 0);
#pragma unroll
            for (int r = 0; r < 4; ++r) {
                float y = c[r] + kbv[ft];
                float e = __expf(2.f * y);
                tsc += qv[ft] * (1.f - 2.f * __builtin_amdgcn_rcpf(e + 1.f));
            }
        }
        {
            float4v c = {0.f, 0.f, 0.f, 0.f};
            c = __builtin_amdgcn_mfma_f32_16x16x32_fp8_fp8(af[0], bf[8][0], c, 0, 0, 0);
            c = __builtin_amdgcn_mfma_f32_16x16x32_fp8_fp8(af[1], bf[8][1], c, 0, 0, 0);
            c = __builtin_amdgcn_mfma_f32_16x16x32_fp8_fp8(af[2], bf[8][2], c, 0, 0, 0);
            c = __builtin_amdgcn_mfma_f32_16x16x32_fp8_fp8(af[3], bf[8][3], c, 0, 0, 0);
            tcs = c[0] + c[1] + c[2] + c[3];
        }
        if (m == 0)      { sc[0] += tsc; cs[0] += tcs; }
        else if (m == 1) { sc[1] += tsc; cs[1] += tcs; }
        else if (m == 2) { sc[2] += tsc; cs[2] += tcs; }
        else             { sc[3] += tsc; cs[3] += tcs; }
        t = tn;
        af[0] = afn[0]; af[1] = afn[1]; af[2] = afn[2]; af[3] = afn[3];
    }

#pragma unroll
    for (int m = 0; m < 4; ++m) {
        float s = sc[m];
#pragma unroll
        for (int off = 1; off < 64; off <<= 1) s += __shfl_xor(s, off);
        if (lane == 0 && s != 0.f) atomicAdd(&redv[m], s);
        float v = cs[m];
        v += __shfl_xor(v, 16);
        v += __shfl_xor(v, 32);
        if (hi == 0 && fi < 2 && v != 0.f) atomicAdd(&redv[4 + 2 * m + fi], v);
    }
    __syncthreads();
    if (tid < 4)              atomicAdd(&score[tid], redv[tid]);
    if (tid >= 4 && tid < 12) atomicAdd(&cs2[tid - 4], redv[tid]);
}

// ---------------------------------------------------------------------------
// Stage 5: semantic softmax + classifier + sigmoid. One thread.
// ---------------------------------------------------------------------------
__global__ void final_kernel(const float* __restrict__ cs2,
                             const float* __restrict__ score,
                             const float* __restrict__ lb,
                             float* __restrict__ out)
{
    float s0 = score[0] / (float)N0;
    float s1 = score[1] / (float)N0;
    float s2 = score[2] / (float)N1;
    float s3 = score[3] / (float)N1;
    float m0 = fmaxf(s0, s1);
    float e0 = expf(s0 - m0), e1 = expf(s1 - m0);
    float a0 = e0 / (e0 + e1), a1 = e1 / (e0 + e1);
    float m1 = fmaxf(s2, s3);
    float e2 = expf(s2 - m1), e3 = expf(s3 - m1);
    float a2 = e2 / (e2 + e3), a3 = e3 / (e2 + e3);
    float z0 = a0 * cs2[0] + a1 * cs2[2] + a2 * cs2[4] + a3 * cs2[6] + lb[0];
    float z1 = a0 * cs2[1] + a1 * cs2[3] + a2 * cs2[5] + a3 * cs2[7] + lb[1];
    out[0] = 1.f / (1.f + expf(-z0));
    out[1] = 1.f / (1.f + expf(-z1));
}

extern "C" void kernel_launch(void* const* d_in, const int* in_sizes, int n_in,
                              void* d_out, int out_size, void* d_ws, size_t ws_size,
                              hipStream_t stream)
{
    const float* x0  = (const float*)d_in[0];
    const float* x1  = (const float*)d_in[1];
    const float* x2  = (const float*)d_in[2];
    const int* ei00  = (const int*)d_in[3];
    const int* ei11  = (const int*)d_in[4];
    const int* ei10  = (const int*)d_in[5];
    const int* ei21  = (const int*)d_in[6];
    const float* W0  = (const float*)d_in[7];  const float* b0 = (const float*)d_in[8];
    const float* W1  = (const float*)d_in[9];  const float* b1 = (const float*)d_in[10];
    const float* W2  = (const float*)d_in[11]; const float* b2 = (const float*)d_in[12];
    const float* as00 = (const float*)d_in[13]; const float* ad00 = (const float*)d_in[14];
    const float* as11 = (const float*)d_in[15]; const float* ad11 = (const float*)d_in[16];
    const float* as10 = (const float*)d_in[17]; const float* ad10 = (const float*)d_in[18];
    const float* as21 = (const float*)d_in[19]; const float* ad21 = (const float*)d_in[20];
    const float* kw  = (const float*)d_in[21]; const float* kb  = (const float*)d_in[22];
    const float* q   = (const float*)d_in[23];
    const float* lw  = (const float*)d_in[24]; const float* lb  = (const float*)d_in[25];
    float* out = (float*)d_out;

    char* p = (char*)d_ws;
    auto alloc = [&](size_t bytes) {
        char* r = p;
        p += (bytes + 255) & ~(size_t)255;
        return r;
    };
    unsigned char* h0 = (unsigned char*)alloc((size_t)N0 * 128);   // fp8 [N][128]
    unsigned char* h1 = (unsigned char*)alloc((size_t)N1 * 128);
    unsigned char* h2 = (unsigned char*)alloc((size_t)N2 * 128);
    float* o_as00 = (float*)alloc((size_t)N0 * 32);
    float* o_ad00 = (float*)alloc((size_t)N0 * 32);
    float* o_as11 = (float*)alloc((size_t)N1 * 32);
    float* o_ad11 = (float*)alloc((size_t)N1 * 32);
    float* o_as10 = (float*)alloc((size_t)N1 * 32);   // src of b10 = cell1
    float* o_ad10 = (float*)alloc((size_t)N0 * 32);   // dst of b10 = cell0
    float* o_as21 = (float*)alloc((size_t)N2 * 32);   // src of b21 = cell2
    float* o_ad21 = (float*)alloc((size_t)N1 * 32);   // dst of b21 = cell1
    int* off    = (int*)alloc((size_t)ND * 4);
    int* cursor = (int*)alloc((size_t)ND * 4);
    int* part   = (int*)alloc((size_t)512 * 4);
    int* srcs   = (int*)alloc((size_t)EE * 4);
    _Float16* wgt = (_Float16*)alloc((size_t)EE * 16);             // f16x8 per edge
    unsigned char* agg = (unsigned char*)alloc((size_t)ND * 128);  // fp8 [u00|b10|u11|b21]
    _Float16* wtg0 = (_Float16*)alloc(128 * 64 * 2);
    _Float16* wtg1 = (_Float16*)alloc(128 * 64 * 2);
    _Float16* wtg2 = (_Float16*)alloc(128 * 64 * 2);
    _Float16* adtg0 = (_Float16*)alloc(32 * 64 * 2);
    _Float16* adtg1 = (_Float16*)alloc(32 * 64 * 2);
    _Float16* adtg2 = (_Float16*)alloc(32 * 64 * 2);
    float* bdcg = (float*)alloc(3 * 32 * 4);
    // ---- zero region (contiguous) ----
    char* zstart = p;
    int* cnt = (int*)alloc((size_t)ND * 4);
    float* colsum2 = (float*)alloc(8 * 4);
    float* score   = (float*)alloc(4 * 4);
    size_t zbytes = (size_t)(p - zstart);

    (void)hipMemsetAsync(zstart, 0, zbytes, stream);

    // prep: transpose W, precompute (W·A)^T and b·A per node type
    PrepT pp0 = {W0, b0, as00, ad00, ad10, nullptr, wtg0, adtg0, bdcg + 0};
    PrepT pp1 = {W1, b1, as11, ad11, as10, ad21,    wtg1, adtg1, bdcg + 32};
    PrepT pp2 = {W2, b2, as21, nullptr, nullptr, nullptr, wtg2, adtg2, bdcg + 64};
    prep_kernel<<<24, 256, 0, stream>>>(pp0, pp1, pp2);

    // fused MFMA projection: blocks [0,296) cell0, [296,880) cell1, [880,1024) cell2
    PT t0 = {x0, b0, h0,
             o_as00, o_ad00, o_ad10, nullptr,
             wtg0, adtg0, bdcg + 0,
             N0, 3125, 0, 296};
    PT t1 = {x1, b1, h1,
             o_as11, o_ad11, o_as10, o_ad21,
             wtg1, adtg1, bdcg + 32,
             N1, 6250, 296, 584};
    PT t2 = {x2, b2, h2,
             o_as21, nullptr, nullptr, nullptr,
             wtg2, adtg2, bdcg + 64,
             N2, 1563, 880, 144};
    proj_mfma<<<1024, 256, 0, stream>>>(t0, t1, t2);

    // CSR build
    count_kernel<<<(EE + 255) / 256, 256, 0, stream>>>(ei00, ei10, ei11, ei21, cnt);
    scan1_kernel<<<NB, 256, 0, stream>>>(cnt, part);
    scan2_kernel<<<1, 256, 0, stream>>>(part);
    scan3_kernel<<<NB, 256, 0, stream>>>(cnt, part, off, cursor);
    fill_kernel<<<(EE + 255) / 256, 256, 0, stream>>>(ei00, ei10, ei11, ei21,
        o_as00, o_ad00, o_as10, o_ad10, o_as11, o_ad11, o_as21, o_ad21,
        cursor, srcs, wgt);

    // gather (4 slots/wave, CSR-ordered weights, fp8 h rows)
    gather_kernel<<<ND / 16, 256, 0, stream>>>(cnt, off, srcs, wgt, h0, h1, h2, agg);

    // fused semantic reduction over all 4 metapaths (fp8 MFMA, register-pinned B)
    semantic_kernel<<<768, 256, 0, stream>>>(agg, kw, lw, kb, q, colsum2, score);

    final_kernel<<<1, 1, 0, stream>>>(colsum2, score, lb, out);
}

// Round 11
// 289.338 us; speedup vs baseline: 1.1848x; 1.0219x over previous
//
#include <hip/hip_runtime.h>
#include <hip/hip_fp16.h>

#define N0 50000
#define N1 100000
#define N2 25000
#define E00 200000
#define E11 200000
#define E10 100000
#define E21 50000
#define EE  550000   // E00+E10+E11+E21 (concatenated edge space)
#define ND  300000   // 50000(u00)+50000(b10)+100000(u11)+100000(b21) dst slots
#define NB  293      // ceil(ND/1024) scan blocks
#define NT_ALL 18750 // ND/16 semantic tiles
#define HID 128
#define INC 64

typedef _Float16 half8 __attribute__((ext_vector_type(8)));
typedef _Float16 half4_t __attribute__((ext_vector_type(4)));
typedef float float4v __attribute__((ext_vector_type(4)));
typedef float floatx2 __attribute__((ext_vector_type(2)));

// ---------------------------------------------------------------------------
// Stage 0 (prep): per node type, write to GLOBAL (f16, L2/L3-resident):
//   wtg[f][g]  = W[g][f]                  (128 x 64)  — MFMA B for h
//   adtg[c][g] = (W·A)^T[c][g]            (32 x 64)   — MFMA B for attn dots
//   bdc[c]     = b·A                      (32 scalars)
// Blocks 24..31 additionally emit kwf8[f][g] = fp8([k_w|lin_w]^T) (144x128 B)
// so semantic_kernel can load its B fragments straight from global.
// ---------------------------------------------------------------------------
struct PrepT {
    const float* W; const float* bias;
    const float* av0; const float* av1; const float* av2; const float* av3;
    _Float16* wtg; _Float16* adtg; float* bdc;
};

__global__ __launch_bounds__(256) void prep_kernel(
    PrepT p0, PrepT p1, PrepT p2,
    const float* __restrict__ kw, const float* __restrict__ lw,
    unsigned char* __restrict__ kwf8)
{
    if (blockIdx.x >= 24) {
        // kwf8: 144 x 128 fp8 = 18432 entries; 8 blocks x 256 threads x 9
        int base = (blockIdx.x - 24) * 256 + threadIdx.x;
        for (int it = 0; it < 9; ++it) {
            int idx = base + it * 2048;
            int f = idx >> 7, g = idx & 127;
            float v;
            if (f < 128)      v = kw[g * 128 + f];
            else if (f < 130) v = lw[g * 2 + (f - 128)];
            else              v = 0.f;
            int r = __builtin_amdgcn_cvt_pk_fp8_f32(v, 0.f, 0, false);
            kwf8[idx] = (unsigned char)r;
        }
        return;
    }
    PrepT P = (blockIdx.x >= 16) ? p2 : (blockIdx.x >= 8) ? p1 : p0;
    const int lb = blockIdx.x & 7;
    const int t2 = lb * 256 + threadIdx.x;   // 0..2047

    // transpose W -> wtg (thread: fixed f, 4 consecutive g, b64 write)
    {
        int f = t2 >> 4, g0 = (t2 & 15) * 4;
        half4_t v;
#pragma unroll
        for (int j = 0; j < 4; ++j) v[j] = (_Float16)P.W[(g0 + j) * 128 + f];
        *(half4_t*)&P.wtg[f * 64 + g0] = v;
    }
    // (W·A)^T -> adtg
    {
        int c = t2 >> 6, g = t2 & 63;
        const float* av = (c < 8) ? P.av0 : (c < 16) ? P.av1 : (c < 24) ? P.av2 : P.av3;
        float v = 0.f;
        if (av) {
            int hh = c & 7;
#pragma unroll
            for (int d = 0; d < 16; ++d)
                v += P.W[g * 128 + hh * 16 + d] * av[hh * 16 + d];
        }
        P.adtg[c * 64 + g] = (_Float16)v;
    }
    // bdc
    if (lb == 0 && threadIdx.x < 32) {
        int c = threadIdx.x;
        const float* av = (c < 8) ? P.av0 : (c < 16) ? P.av1 : (c < 24) ? P.av2 : P.av3;
        float v = 0.f;
        if (av) {
            int hh = c & 7;
#pragma unroll
            for (int d = 0; d < 16; ++d)
                v += P.bias[hh * 16 + d] * av[hh * 16 + d];
        }
        P.bdc[c] = v;
    }
}

// ---------------------------------------------------------------------------
// Stage 1 (fused, MFMA): per node type, h = x @ W + b (fp8 e4m3, [N][128] B)
// and attention dots (fp32 [N][8]). B fragments loaded ONCE from global
// prep buffers. __launch_bounds__(256,2) -> fragments stay register-resident.
// mfma_f32_16x16x32_f16: A[m=lane&15][k=(lane>>4)*8+j]; B[k][n=lane&15];
// C: col=lane&15, row=(lane>>4)*4+reg.
// ---------------------------------------------------------------------------
struct PT {
    const float* x; const float* bias; unsigned char* h;
    float* ao0; float* ao1; float* ao2; float* ao3;
    const _Float16* wtg; const _Float16* adtg; const float* bdc;
    int N; int ntiles; int bstart; int nblocks;
};

#define HPAD 136  // halves; row stride 272 B (16B-aligned b128 reads)

__global__ __launch_bounds__(256, 2) void proj_mfma(PT t0, PT t1, PT t2)
{
    __shared__ _Float16 ht[4][16][HPAD];   // 17.4 KB: per-wave h tile (f16)
    const int tid = threadIdx.x;
    const int lane = tid & 63, wv = tid >> 6;
    const int fi = lane & 15, hi = lane >> 4;

    PT A = (blockIdx.x >= t2.bstart) ? t2 : (blockIdx.x >= t1.bstart) ? t1 : t0;

    // persistent B fragments straight from global (16 B/lane each, L2-hit)
    half8 bfr[8][2], bd[2][2];
#pragma unroll
    for (int nt = 0; nt < 8; ++nt)
#pragma unroll
        for (int kb = 0; kb < 2; ++kb)
            bfr[nt][kb] = *(const half8*)&A.wtg[(nt * 16 + fi) * 64 + kb * 32 + hi * 8];
#pragma unroll
    for (int t = 0; t < 2; ++t)
#pragma unroll
        for (int kb = 0; kb < 2; ++kb)
            bd[t][kb] = *(const half8*)&A.adtg[(t * 16 + fi) * 64 + kb * 32 + hi * 8];

    float bvv[8];
#pragma unroll
    for (int nt = 0; nt < 8; ++nt) bvv[nt] = A.bias[nt * 16 + fi];
    const float bdc0 = A.bdc[fi];
    const float bdc1 = A.bdc[16 + fi];

    float* aolo = (fi >= 8) ? A.ao1 : A.ao0;
    float* aohi = (fi >= 8) ? A.ao3 : A.ao2;
    const bool has_hi = (A.ao2 != nullptr) || (A.ao3 != nullptr);

    const int stride = A.nblocks * 4;
    for (int t = (blockIdx.x - A.bstart) * 4 + wv; t < A.ntiles; t += stride) {
        const int base = t * 16;
        int rsrc = base + fi; if (rsrc >= A.N) rsrc = A.N - 1;
        const float* xp = A.x + (size_t)rsrc * 64 + hi * 8;
        float4 u0 = *(const float4*)(xp);
        float4 u1 = *(const float4*)(xp + 4);
        float4 u2 = *(const float4*)(xp + 32);
        float4 u3 = *(const float4*)(xp + 36);
        half8 a0, a1;
        a0[0] = (_Float16)u0.x; a0[1] = (_Float16)u0.y; a0[2] = (_Float16)u0.z; a0[3] = (_Float16)u0.w;
        a0[4] = (_Float16)u1.x; a0[5] = (_Float16)u1.y; a0[6] = (_Float16)u1.z; a0[7] = (_Float16)u1.w;
        a1[0] = (_Float16)u2.x; a1[1] = (_Float16)u2.y; a1[2] = (_Float16)u2.z; a1[3] = (_Float16)u2.w;
        a1[4] = (_Float16)u3.x; a1[5] = (_Float16)u3.y; a1[6] = (_Float16)u3.z; a1[7] = (_Float16)u3.w;

        float4v c[8];
#pragma unroll
        for (int nt = 0; nt < 8; ++nt) {
            float4v z = {0.f, 0.f, 0.f, 0.f};
            z = __builtin_amdgcn_mfma_f32_16x16x32_f16(a0, bfr[nt][0], z, 0, 0, 0);
            z = __builtin_amdgcn_mfma_f32_16x16x32_f16(a1, bfr[nt][1], z, 0, 0, 0);
            c[nt] = z;
        }
        float4v d0 = {0.f, 0.f, 0.f, 0.f};
        d0 = __builtin_amdgcn_mfma_f32_16x16x32_f16(a0, bd[0][0], d0, 0, 0, 0);
        d0 = __builtin_amdgcn_mfma_f32_16x16x32_f16(a1, bd[0][1], d0, 0, 0, 0);
        float4v d1 = {0.f, 0.f, 0.f, 0.f};
        if (has_hi) {
            d1 = __builtin_amdgcn_mfma_f32_16x16x32_f16(a0, bd[1][0], d1, 0, 0, 0);
            d1 = __builtin_amdgcn_mfma_f32_16x16x32_f16(a1, bd[1][1], d1, 0, 0, 0);
        }

        // h epilogue: C frags -> per-wave LDS tile -> fp8 coalesced stores
#pragma unroll
        for (int nt = 0; nt < 8; ++nt)
#pragma unroll
            for (int r = 0; r < 4; ++r)
                ht[wv][hi * 4 + r][nt * 16 + fi] = (_Float16)(c[nt][r] + bvv[nt]);
#pragma unroll
        for (int i = 0; i < 4; ++i) {
            int row = i * 4 + hi;
            int node = base + row;
            if (node < A.N) {
                half8 v = *(const half8*)&ht[wv][row][fi * 8];
                int pa = __builtin_amdgcn_cvt_pk_fp8_f32((float)v[0], (float)v[1], 0, false);
                pa = __builtin_amdgcn_cvt_pk_fp8_f32((float)v[2], (float)v[3], pa, true);
                int pb = __builtin_amdgcn_cvt_pk_fp8_f32((float)v[4], (float)v[5], 0, false);
                pb = __builtin_amdgcn_cvt_pk_fp8_f32((float)v[6], (float)v[7], pb, true);
                int2 o = {pa, pb};
                *(int2*)(A.h + (size_t)node * 128 + fi * 8) = o;
            }
        }
        if (aolo) {
#pragma unroll
            for (int r = 0; r < 4; ++r) {
                int node = base + hi * 4 + r;
                if (node < A.N) aolo[(size_t)node * 8 + (fi & 7)] = d0[r] + bdc0;
            }
        }
        if (aohi) {
#pragma unroll
            for (int r = 0; r < 4; ++r) {
                int node = base + hi * 4 + r;
                if (node < A.N) aohi[(size_t)node * 8 + (fi & 7)] = d1[r] + bdc1;
            }
        }
    }
}

// ---------------------------------------------------------------------------
// CSR build over the concatenated (edge-type, dst) slot space.
// ---------------------------------------------------------------------------
__device__ __forceinline__ void decode_edge(
    int e, const int* ei00, const int* ei10, const int* ei11, const int* ei21,
    int& src, int& slot)
{
    if (e < E00)                    { src = ei00[e];               slot = ei00[E00 + e]; }
    else if (e < E00 + E10)         { int i = e - E00;             src = ei10[i]; slot = 50000  + ei10[E10 + i]; }
    else if (e < E00 + E10 + E11)   { int i = e - E00 - E10;       src = ei11[i]; slot = 100000 + ei11[E11 + i]; }
    else                            { int i = e - E00 - E10 - E11; src = ei21[i]; slot = 200000 + ei21[E21 + i]; }
}

__global__ __launch_bounds__(256) void count_kernel(
    const int* __restrict__ ei00, const int* __restrict__ ei10,
    const int* __restrict__ ei11, const int* __restrict__ ei21,
    int* __restrict__ cnt)
{
    int e = blockIdx.x * 256 + threadIdx.x;
    if (e >= EE) return;
    int src, slot;
    decode_edge(e, ei00, ei10, ei11, ei21, src, slot);
    atomicAdd(&cnt[slot], 1);
}

__global__ __launch_bounds__(256) void scan1_kernel(
    const int* __restrict__ cnt, int* __restrict__ part)
{
    const int tid = threadIdx.x, b = blockIdx.x;
    int i0 = b * 1024 + tid * 4;
    int s = 0;
#pragma unroll
    for (int k = 0; k < 4; ++k) { int i = i0 + k; s += (i < ND) ? cnt[i] : 0; }
#pragma unroll
    for (int off = 1; off < 64; off <<= 1) s += __shfl_xor(s, off);
    __shared__ int wt[4];
    if ((tid & 63) == 0) wt[tid >> 6] = s;
    __syncthreads();
    if (tid == 0) part[b] = wt[0] + wt[1] + wt[2] + wt[3];
}

__global__ __launch_bounds__(256) void scan2_kernel(int* __restrict__ part)
{
    const int t = threadIdx.x;
    int p0 = (2 * t     < NB) ? part[2 * t]     : 0;
    int p1 = (2 * t + 1 < NB) ? part[2 * t + 1] : 0;
    int ps = p0 + p1;
    __shared__ int sd[256];
    sd[t] = ps; __syncthreads();
    for (int d = 1; d < 256; d <<= 1) {
        int v = (t >= d) ? sd[t - d] : 0;
        __syncthreads();
        sd[t] += v;
        __syncthreads();
    }
    int exc = sd[t] - ps;
    if (2 * t     < NB) part[2 * t]     = exc;
    if (2 * t + 1 < NB) part[2 * t + 1] = exc + p0;
}

__global__ __launch_bounds__(256) void scan3_kernel(
    const int* __restrict__ cnt, const int* __restrict__ part,
    int* __restrict__ off, int* __restrict__ cursor)
{
    const int tid = threadIdx.x, b = blockIdx.x;
    const int lane = tid & 63, wv = tid >> 6;
    int i0 = b * 1024 + tid * 4;
    int v[4];
#pragma unroll
    for (int k = 0; k < 4; ++k) { int i = i0 + k; v[k] = (i < ND) ? cnt[i] : 0; }
    int ts = v[0] + v[1] + v[2] + v[3];
    int inc = ts;
#pragma unroll
    for (int d = 1; d < 64; d <<= 1) {
        int u = __shfl_up(inc, d);
        if (lane >= d) inc += u;
    }
    int wexc = inc - ts;
    __shared__ int wt[4];
    if (lane == 63) wt[wv] = inc;
    __syncthreads();
    int wbase = 0;
    for (int w = 0; w < wv; ++w) wbase += wt[w];
    int base = part[b] + wbase + wexc;
    int pre = 0;
#pragma unroll
    for (int k = 0; k < 4; ++k) {
        int i = i0 + k;
        if (i < ND) { off[i] = base + pre; cursor[i] = base + pre; }
        pre += v[k];
    }
}

// ---------------------------------------------------------------------------
// Fill: place src ids in CSR order AND precompute the 8 per-head softmax
// numerators w = exp(leaky_relu(a_s + a_d)) for each edge (f16x8, CSR order).
// ---------------------------------------------------------------------------
__global__ __launch_bounds__(256) void fill_kernel(
    const int* __restrict__ ei00, const int* __restrict__ ei10,
    const int* __restrict__ ei11, const int* __restrict__ ei21,
    const float* __restrict__ as00, const float* __restrict__ ad00,
    const float* __restrict__ as10, const float* __restrict__ ad10,
    const float* __restrict__ as11, const float* __restrict__ ad11,
    const float* __restrict__ as21, const float* __restrict__ ad21,
    int* __restrict__ cursor, int* __restrict__ srcs, _Float16* __restrict__ wgt)
{
    int e = blockIdx.x * 256 + threadIdx.x;
    if (e >= EE) return;
    int src, d, slot;
    const float* asp; const float* adp;
    if (e < E00) {
        src = ei00[e]; d = ei00[E00 + e]; slot = d; asp = as00; adp = ad00;
    } else if (e < E00 + E10) {
        int i = e - E00; src = ei10[i]; d = ei10[E10 + i]; slot = 50000 + d; asp = as10; adp = ad10;
    } else if (e < E00 + E10 + E11) {
        int i = e - E00 - E10; src = ei11[i]; d = ei11[E11 + i]; slot = 100000 + d; asp = as11; adp = ad11;
    } else {
        int i = e - E00 - E10 - E11; src = ei21[i]; d = ei21[E21 + i]; slot = 200000 + d; asp = as21; adp = ad21;
    }
    float4 sa0 = *(const float4*)(asp + (size_t)src * 8);
    float4 sa1 = *(const float4*)(asp + (size_t)src * 8 + 4);
    float4 da0 = *(const float4*)(adp + (size_t)d * 8);
    float4 da1 = *(const float4*)(adp + (size_t)d * 8 + 4);
    float vv[8] = {sa0.x + da0.x, sa0.y + da0.y, sa0.z + da0.z, sa0.w + da0.w,
                   sa1.x + da1.x, sa1.y + da1.y, sa1.z + da1.z, sa1.w + da1.w};
    half8 w;
#pragma unroll
    for (int h = 0; h < 8; ++h) {
        float v = vv[h];
        v = v > 0.f ? v : 0.2f * v;
        w[h] = (_Float16)__expf(v);
    }
    int pos = atomicAdd(&cursor[slot], 1);
    srcs[pos] = src;
    *(half8*)(wgt + (size_t)pos * 8) = w;
}

// ---------------------------------------------------------------------------
// Gather: 4 slots per wave, 16 lanes per slot; lane covers 8 fp8 features
// (one b64 load per edge), head = (lane&15)>>1. Weights read sequentially
// from the CSR-ordered wgt array. agg (fp8, relu'ed) written exactly once.
// ---------------------------------------------------------------------------
__global__ __launch_bounds__(256) void gather_kernel(
    const int* __restrict__ cnt, const int* __restrict__ off,
    const int* __restrict__ srcs, const _Float16* __restrict__ wgt,
    const unsigned char* __restrict__ h0, const unsigned char* __restrict__ h1,
    const unsigned char* __restrict__ h2,
    unsigned char* __restrict__ agg)
{
    const int gid = blockIdx.x * 256 + threadIdx.x;
    const int lane = gid & 63;
    const int grp = lane >> 4, lg = lane & 15;
    const int slot = (gid >> 6) * 4 + grp;          // grid sized so slot < ND
    const int head = lg >> 1;
    const unsigned char* hs = (slot < 50000) ? h0 : (slot < 200000) ? h1 : h2;
    const int deg = cnt[slot], st = off[slot];

    int degm = deg;
    degm = max(degm, __shfl_xor(degm, 16));
    degm = max(degm, __shfl_xor(degm, 32));

    float acc[8] = {0.f, 0.f, 0.f, 0.f, 0.f, 0.f, 0.f, 0.f};
    float sw = 0.f;
    int i = 0;
    for (; i + 2 <= degm; i += 2) {
        bool a0 = (i < deg), a1 = (i + 1 < deg);
        int s0 = 0, s1 = 0;
        if (a0) s0 = srcs[st + i];
        if (a1) s1 = srcs[st + i + 1];
        float w0 = 0.f, w1 = 0.f;
        unsigned long long v0 = 0, v1 = 0;
        if (a0) { w0 = (float)wgt[(size_t)(st + i) * 8 + head];
                  v0 = *(const unsigned long long*)(hs + (size_t)s0 * 128 + lg * 8); }
        if (a1) { w1 = (float)wgt[(size_t)(st + i + 1) * 8 + head];
                  v1 = *(const unsigned long long*)(hs + (size_t)s1 * 128 + lg * 8); }
        int l0 = (int)(v0 & 0xffffffffu), m0 = (int)(v0 >> 32);
        int l1 = (int)(v1 & 0xffffffffu), m1 = (int)(v1 >> 32);
        floatx2 f0a = __builtin_amdgcn_cvt_pk_f32_fp8(l0, false);
        floatx2 f0b = __builtin_amdgcn_cvt_pk_f32_fp8(l0, true);
        floatx2 f0c = __builtin_amdgcn_cvt_pk_f32_fp8(m0, false);
        floatx2 f0d = __builtin_amdgcn_cvt_pk_f32_fp8(m0, true);
        floatx2 f1a = __builtin_amdgcn_cvt_pk_f32_fp8(l1, false);
        floatx2 f1b = __builtin_amdgcn_cvt_pk_f32_fp8(l1, true);
        floatx2 f1c = __builtin_amdgcn_cvt_pk_f32_fp8(m1, false);
        floatx2 f1d = __builtin_amdgcn_cvt_pk_f32_fp8(m1, true);
        acc[0] += w0 * f0a.x + w1 * f1a.x;
        acc[1] += w0 * f0a.y + w1 * f1a.y;
        acc[2] += w0 * f0b.x + w1 * f1b.x;
        acc[3] += w0 * f0b.y + w1 * f1b.y;
        acc[4] += w0 * f0c.x + w1 * f1c.x;
        acc[5] += w0 * f0c.y + w1 * f1c.y;
        acc[6] += w0 * f0d.x + w1 * f1d.x;
        acc[7] += w0 * f0d.y + w1 * f1d.y;
        sw += w0 + w1;
    }
    if (i < degm) {
        bool a0 = (i < deg);
        int s0 = 0;
        if (a0) s0 = srcs[st + i];
        float w0 = 0.f;
        unsigned long long v0 = 0;
        if (a0) { w0 = (float)wgt[(size_t)(st + i) * 8 + head];
                  v0 = *(const unsigned long long*)(hs + (size_t)s0 * 128 + lg * 8); }
        int l0 = (int)(v0 & 0xffffffffu), m0 = (int)(v0 >> 32);
        floatx2 f0a = __builtin_amdgcn_cvt_pk_f32_fp8(l0, false);
        floatx2 f0b = __builtin_amdgcn_cvt_pk_f32_fp8(l0, true);
        floatx2 f0c = __builtin_amdgcn_cvt_pk_f32_fp8(m0, false);
        floatx2 f0d = __builtin_amdgcn_cvt_pk_f32_fp8(m0, true);
        acc[0] += w0 * f0a.x; acc[1] += w0 * f0a.y;
        acc[2] += w0 * f0b.x; acc[3] += w0 * f0b.y;
        acc[4] += w0 * f0c.x; acc[5] += w0 * f0c.y;
        acc[6] += w0 * f0d.x; acc[7] += w0 * f0d.y;
        sw += w0;
    }

    float rr = __builtin_amdgcn_rcpf(sw + 1e-16f);
    float r[8];
#pragma unroll
    for (int j = 0; j < 8; ++j) r[j] = fmaxf(acc[j] * rr, 0.f);   // relu here
    int pa = __builtin_amdgcn_cvt_pk_fp8_f32(r[0], r[1], 0, false);
    pa = __builtin_amdgcn_cvt_pk_fp8_f32(r[2], r[3], pa, true);
    int pb = __builtin_amdgcn_cvt_pk_fp8_f32(r[4], r[5], 0, false);
    pb = __builtin_amdgcn_cvt_pk_fp8_f32(r[6], r[7], pb, true);
    int2 o = {pa, pb};
    *(int2*)(agg + (size_t)slot * 128 + lg * 8) = o;
}

// ---------------------------------------------------------------------------
// Stage 4 (fused, fp8 MFMA over all 4 metapaths): Y = agg_relu @ [k_w|lin_w].
// B fragments loaded ONCE from the prep-built global kwf8 (no kw LDS at all —
// same recipe that fixed proj_mfma). __launch_bounds__(256,2) for the VGPR
// budget. Next-tile A prefetch. metapath: 3=t>=12500, 2=t>=6250, 1=t>=3125.
// ---------------------------------------------------------------------------
__global__ __launch_bounds__(256, 2) void semantic_kernel(
    const unsigned char* __restrict__ agg, const unsigned char* __restrict__ kwf8,
    const float* __restrict__ kb, const float* __restrict__ q,
    float* __restrict__ cs2, float* __restrict__ score)
{
    __shared__ float redv[12];
    const int tid = threadIdx.x;
    const int lane = tid & 63, wv = tid >> 6;
    const int fi = lane & 15, hi = lane >> 4;

    if (tid < 12) redv[tid] = 0.f;
    __syncthreads();

    // persistent B fragments straight from global (8 B/lane each, L2-hit)
    long bf[9][4];
#pragma unroll
    for (int ft = 0; ft < 9; ++ft)
#pragma unroll
        for (int kk = 0; kk < 4; ++kk)
            bf[ft][kk] = *(const long*)&kwf8[(ft * 16 + fi) * 128 + kk * 32 + hi * 8];

    float qv[8], kbv[8];
#pragma unroll
    for (int ft = 0; ft < 8; ++ft) {
        qv[ft] = q[ft * 16 + fi];
        kbv[ft] = kb[ft * 16 + fi];
    }

    float sc[4] = {0.f, 0.f, 0.f, 0.f};
    float cs[4] = {0.f, 0.f, 0.f, 0.f};
    const int wid = blockIdx.x * 4 + wv;
    const int nw = gridDim.x * 4;

    long af[4] = {0, 0, 0, 0};
    int t = wid;
    if (t < NT_ALL) {
        const unsigned char* rowp = agg + ((size_t)(t * 16 + fi) * 128 + hi * 8);
        af[0] = *(const long*)(rowp);
        af[1] = *(const long*)(rowp + 32);
        af[2] = *(const long*)(rowp + 64);
        af[3] = *(const long*)(rowp + 96);
    }
    while (t < NT_ALL) {
        const int tn = t + nw;
        long afn[4] = {0, 0, 0, 0};
        if (tn < NT_ALL) {
            const unsigned char* rowp = agg + ((size_t)(tn * 16 + fi) * 128 + hi * 8);
            afn[0] = *(const long*)(rowp);
            afn[1] = *(const long*)(rowp + 32);
            afn[2] = *(const long*)(rowp + 64);
            afn[3] = *(const long*)(rowp + 96);
        }
        const int m = (t >= 12500) ? 3 : (t >= 6250) ? 2 : (t >= 3125) ? 1 : 0;
        float tsc = 0.f, tcs;
#pragma unroll
        for (int ft = 0; ft < 8; ++ft) {
            float4v c = {0.f, 0.f, 0.f, 0.f};
            c = __builtin_amdgcn_mfma_f32_16x16x32_fp8_fp8(af[0], bf[ft][0], c, 0, 0, 0);
            c = __builtin_amdgcn_mfma_f32_16x16x32_fp8_fp8(af[1], bf[ft][1], c, 0, 0, 0);
            c = __builtin_amdgcn_mfma_f32_16x16x32_fp8_fp8(af[2], bf[ft][2], c, 0, 0, 0);
            c = __builtin_amdgcn_mfma_f32_16x16x32_fp8_fp8(af[3], bf[ft][3], c, 0, 0, 0);
#pragma unroll
            for (int r = 0; r < 4; ++r) {
                float y = c[r] + kbv[ft];
                float e = __expf(2.f * y);
                tsc += qv[ft] * (1.f - 2.f * __builtin_amdgcn_rcpf(e + 1.f));
            }
        }
        {
            float4v c = {0.f, 0.f, 0.f, 0.f};
            c = __builtin_amdgcn_mfma_f32_16x16x32_fp8_fp8(af[0], bf[8][0], c, 0, 0, 0);
            c = __builtin_amdgcn_mfma_f32_16x16x32_fp8_fp8(af[1], bf[8][1], c, 0, 0, 0);
            c = __builtin_amdgcn_mfma_f32_16x16x32_fp8_fp8(af[2], bf[8][2], c, 0, 0, 0);
            c = __builtin_amdgcn_mfma_f32_16x16x32_fp8_fp8(af[3], bf[8][3], c, 0, 0, 0);
            tcs = c[0] + c[1] + c[2] + c[3];
        }
        if (m == 0)      { sc[0] += tsc; cs[0] += tcs; }
        else if (m == 1) { sc[1] += tsc; cs[1] += tcs; }
        else if (m == 2) { sc[2] += tsc; cs[2] += tcs; }
        else             { sc[3] += tsc; cs[3] += tcs; }
        t = tn;
        af[0] = afn[0]; af[1] = afn[1]; af[2] = afn[2]; af[3] = afn[3];
    }

#pragma unroll
    for (int m = 0; m < 4; ++m) {
        float s = sc[m];
#pragma unroll
        for (int off = 1; off < 64; off <<= 1) s += __shfl_xor(s, off);
        if (lane == 0 && s != 0.f) atomicAdd(&redv[m], s);
        float v = cs[m];
        v += __shfl_xor(v, 16);
        v += __shfl_xor(v, 32);
        if (hi == 0 && fi < 2 && v != 0.f) atomicAdd(&redv[4 + 2 * m + fi], v);
    }
    __syncthreads();
    if (tid < 4)              atomicAdd(&score[tid], redv[tid]);
    if (tid >= 4 && tid < 12) atomicAdd(&cs2[tid - 4], redv[tid]);
}

// ---------------------------------------------------------------------------
// Stage 5: semantic softmax + classifier + sigmoid. One thread.
// ---------------------------------------------------------------------------
__global__ void final_kernel(const float* __restrict__ cs2,
                             const float* __restrict__ score,
                             const float* __restrict__ lb,
                             float* __restrict__ out)
{
    float s0 = score[0] / (float)N0;
    float s1 = score[1] / (float)N0;
    float s2 = score[2] / (float)N1;
    float s3 = score[3] / (float)N1;
    float m0 = fmaxf(s0, s1);
    float e0 = expf(s0 - m0), e1 = expf(s1 - m0);
    float a0 = e0 / (e0 + e1), a1 = e1 / (e0 + e1);
    float m1 = fmaxf(s2, s3);
    float e2 = expf(s2 - m1), e3 = expf(s3 - m1);
    float a2 = e2 / (e2 + e3), a3 = e3 / (e2 + e3);
    float z0 = a0 * cs2[0] + a1 * cs2[2] + a2 * cs2[4] + a3 * cs2[6] + lb[0];
    float z1 = a0 * cs2[1] + a1 * cs2[3] + a2 * cs2[5] + a3 * cs2[7] + lb[1];
    out[0] = 1.f / (1.f + expf(-z0));
    out[1] = 1.f / (1.f + expf(-z1));
}

extern "C" void kernel_launch(void* const* d_in, const int* in_sizes, int n_in,
                              void* d_out, int out_size, void* d_ws, size_t ws_size,
                              hipStream_t stream)
{
    const float* x0  = (const float*)d_in[0];
    const float* x1  = (const float*)d_in[1];
    const float* x2  = (const float*)d_in[2];
    const int* ei00  = (const int*)d_in[3];
    const int* ei11  = (const int*)d_in[4];
    const int* ei10  = (const int*)d_in[5];
    const int* ei21  = (const int*)d_in[6];
    const float* W0  = (const float*)d_in[7];  const float* b0 = (const float*)d_in[8];
    const float* W1  = (const float*)d_in[9];  const float* b1 = (const float*)d_in[10];
    const float* W2  = (const float*)d_in[11]; const float* b2 = (const float*)d_in[12];
    const float* as00 = (const float*)d_in[13]; const float* ad00 = (const float*)d_in[14];
    const float* as11 = (const float*)d_in[15]; const float* ad11 = (const float*)d_in[16];
    const float* as10 = (const float*)d_in[17]; const float* ad10 = (const float*)d_in[18];
    const float* as21 = (const float*)d_in[19]; const float* ad21 = (const float*)d_in[20];
    const float* kw  = (const float*)d_in[21]; const float* kb  = (const float*)d_in[22];
    const float* q   = (const float*)d_in[23];
    const float* lw  = (const float*)d_in[24]; const float* lb  = (const float*)d_in[25];
    float* out = (float*)d_out;

    char* p = (char*)d_ws;
    auto alloc = [&](size_t bytes) {
        char* r = p;
        p += (bytes + 255) & ~(size_t)255;
        return r;
    };
    unsigned char* h0 = (unsigned char*)alloc((size_t)N0 * 128);   // fp8 [N][128]
    unsigned char* h1 = (unsigned char*)alloc((size_t)N1 * 128);
    unsigned char* h2 = (unsigned char*)alloc((size_t)N2 * 128);
    float* o_as00 = (float*)alloc((size_t)N0 * 32);
    float* o_ad00 = (float*)alloc((size_t)N0 * 32);
    float* o_as11 = (float*)alloc((size_t)N1 * 32);
    float* o_ad11 = (float*)alloc((size_t)N1 * 32);
    float* o_as10 = (float*)alloc((size_t)N1 * 32);   // src of b10 = cell1
    float* o_ad10 = (float*)alloc((size_t)N0 * 32);   // dst of b10 = cell0
    float* o_as21 = (float*)alloc((size_t)N2 * 32);   // src of b21 = cell2
    float* o_ad21 = (float*)alloc((size_t)N1 * 32);   // dst of b21 = cell1
    int* off    = (int*)alloc((size_t)ND * 4);
    int* cursor = (int*)alloc((size_t)ND * 4);
    int* part   = (int*)alloc((size_t)512 * 4);
    int* srcs   = (int*)alloc((size_t)EE * 4);
    _Float16* wgt = (_Float16*)alloc((size_t)EE * 16);             // f16x8 per edge
    unsigned char* agg = (unsigned char*)alloc((size_t)ND * 128);  // fp8 [u00|b10|u11|b21]
    _Float16* wtg0 = (_Float16*)alloc(128 * 64 * 2);
    _Float16* wtg1 = (_Float16*)alloc(128 * 64 * 2);
    _Float16* wtg2 = (_Float16*)alloc(128 * 64 * 2);
    _Float16* adtg0 = (_Float16*)alloc(32 * 64 * 2);
    _Float16* adtg1 = (_Float16*)alloc(32 * 64 * 2);
    _Float16* adtg2 = (_Float16*)alloc(32 * 64 * 2);
    float* bdcg = (float*)alloc(3 * 32 * 4);
    unsigned char* kwf8 = (unsigned char*)alloc(144 * 128);
    // ---- zero region (contiguous) ----
    char* zstart = p;
    int* cnt = (int*)alloc((size_t)ND * 4);
    float* colsum2 = (float*)alloc(8 * 4);
    float* score   = (float*)alloc(4 * 4);
    size_t zbytes = (size_t)(p - zstart);

    (void)hipMemsetAsync(zstart, 0, zbytes, stream);

    // prep: transpose W, precompute (W·A)^T, b·A, and fp8 [k_w|lin_w]^T
    PrepT pp0 = {W0, b0, as00, ad00, ad10, nullptr, wtg0, adtg0, bdcg + 0};
    PrepT pp1 = {W1, b1, as11, ad11, as10, ad21,    wtg1, adtg1, bdcg + 32};
    PrepT pp2 = {W2, b2, as21, nullptr, nullptr, nullptr, wtg2, adtg2, bdcg + 64};
    prep_kernel<<<32, 256, 0, stream>>>(pp0, pp1, pp2, kw, lw, kwf8);

    // fused MFMA projection: blocks [0,296) cell0, [296,880) cell1, [880,1024) cell2
    PT t0 = {x0, b0, h0,
             o_as00, o_ad00, o_ad10, nullptr,
             wtg0, adtg0, bdcg + 0,
             N0, 3125, 0, 296};
    PT t1 = {x1, b1, h1,
             o_as11, o_ad11, o_as10, o_ad21,
             wtg1, adtg1, bdcg + 32,
             N1, 6250, 296, 584};
    PT t2 = {x2, b2, h2,
             o_as21, nullptr, nullptr, nullptr,
             wtg2, adtg2, bdcg + 64,
             N2, 1563, 880, 144};
    proj_mfma<<<1024, 256, 0, stream>>>(t0, t1, t2);

    // CSR build
    count_kernel<<<(EE + 255) / 256, 256, 0, stream>>>(ei00, ei10, ei11, ei21, cnt);
    scan1_kernel<<<NB, 256, 0, stream>>>(cnt, part);
    scan2_kernel<<<1, 256, 0, stream>>>(part);
    scan3_kernel<<<NB, 256, 0, stream>>>(cnt, part, off, cursor);
    fill_kernel<<<(EE + 255) / 256, 256, 0, stream>>>(ei00, ei10, ei11, ei21,
        o_as00, o_ad00, o_as10, o_ad10, o_as11, o_ad11, o_as21, o_ad21,
        cursor, srcs, wgt);

    // gather (4 slots/wave, CSR-ordered weights, fp8 h rows)
    gather_kernel<<<ND / 16, 256, 0, stream>>>(cnt, off, srcs, wgt, h0, h1, h2, agg);

    // fused semantic reduction over all 4 metapaths (fp8 MFMA, global B frags)
    semantic_kernel<<<1024, 256, 0, stream>>>(agg, kwf8, kb, q, colsum2, score);

    final_kernel<<<1, 1, 0, stream>>>(colsum2, score, lb, out);
}

// Round 12
// 283.081 us; speedup vs baseline: 1.2109x; 1.0221x over previous
//
#include <hip/hip_runtime.h>
#include <hip/hip_fp16.h>

#define N0 50000
#define N1 100000
#define N2 25000
#define E00 200000
#define E11 200000
#define E10 100000
#define E21 50000
#define EE  550000   // E00+E10+E11+E21 (concatenated edge space)
#define ND  300000   // 50000(u00)+50000(b10)+100000(u11)+100000(b21) dst slots
#define NB  293      // ceil(ND/1024) scan blocks
#define NT_ALL 18750 // ND/16 semantic tiles
#define HID 128
#define INC 64

typedef _Float16 half8 __attribute__((ext_vector_type(8)));
typedef _Float16 half4_t __attribute__((ext_vector_type(4)));
typedef float float4v __attribute__((ext_vector_type(4)));
typedef float floatx2 __attribute__((ext_vector_type(2)));

// ---------------------------------------------------------------------------
// Kernel A: prep (+count fused, independent work co-runs).
//   blocks 0..23  : per node type wtg/adtg/bdc (f16, L2-resident)
//   blocks 24..31 : kwf8 = fp8([k_w|lin_w]^T) for semantic
//   blocks 32..   : count edges into cnt[slot]
// ---------------------------------------------------------------------------
struct PrepT {
    const float* W; const float* bias;
    const float* av0; const float* av1; const float* av2; const float* av3;
    _Float16* wtg; _Float16* adtg; float* bdc;
};

__device__ __forceinline__ void decode_edge(
    int e, const int* ei00, const int* ei10, const int* ei11, const int* ei21,
    int& src, int& slot)
{
    if (e < E00)                    { src = ei00[e];               slot = ei00[E00 + e]; }
    else if (e < E00 + E10)         { int i = e - E00;             src = ei10[i]; slot = 50000  + ei10[E10 + i]; }
    else if (e < E00 + E10 + E11)   { int i = e - E00 - E10;       src = ei11[i]; slot = 100000 + ei11[E11 + i]; }
    else                            { int i = e - E00 - E10 - E11; src = ei21[i]; slot = 200000 + ei21[E21 + i]; }
}

__global__ __launch_bounds__(256) void prep_kernel(
    PrepT p0, PrepT p1, PrepT p2,
    const float* __restrict__ kw, const float* __restrict__ lw,
    unsigned char* __restrict__ kwf8,
    const int* __restrict__ ei00, const int* __restrict__ ei10,
    const int* __restrict__ ei11, const int* __restrict__ ei21,
    int* __restrict__ cnt)
{
    if (blockIdx.x >= 32) {
        int e = (blockIdx.x - 32) * 256 + threadIdx.x;
        if (e >= EE) return;
        int src, slot;
        decode_edge(e, ei00, ei10, ei11, ei21, src, slot);
        atomicAdd(&cnt[slot], 1);
        return;
    }
    if (blockIdx.x >= 24) {
        int base = (blockIdx.x - 24) * 256 + threadIdx.x;
        for (int it = 0; it < 9; ++it) {
            int idx = base + it * 2048;
            int f = idx >> 7, g = idx & 127;
            float v;
            if (f < 128)      v = kw[g * 128 + f];
            else if (f < 130) v = lw[g * 2 + (f - 128)];
            else              v = 0.f;
            int r = __builtin_amdgcn_cvt_pk_fp8_f32(v, 0.f, 0, false);
            kwf8[idx] = (unsigned char)r;
        }
        return;
    }
    PrepT P = (blockIdx.x >= 16) ? p2 : (blockIdx.x >= 8) ? p1 : p0;
    const int lb = blockIdx.x & 7;
    const int t2 = lb * 256 + threadIdx.x;   // 0..2047
    {
        int f = t2 >> 4, g0 = (t2 & 15) * 4;
        half4_t v;
#pragma unroll
        for (int j = 0; j < 4; ++j) v[j] = (_Float16)P.W[(g0 + j) * 128 + f];
        *(half4_t*)&P.wtg[f * 64 + g0] = v;
    }
    {
        int c = t2 >> 6, g = t2 & 63;
        const float* av = (c < 8) ? P.av0 : (c < 16) ? P.av1 : (c < 24) ? P.av2 : P.av3;
        float v = 0.f;
        if (av) {
            int hh = c & 7;
#pragma unroll
            for (int d = 0; d < 16; ++d)
                v += P.W[g * 128 + hh * 16 + d] * av[hh * 16 + d];
        }
        P.adtg[c * 64 + g] = (_Float16)v;
    }
    if (lb == 0 && threadIdx.x < 32) {
        int c = threadIdx.x;
        const float* av = (c < 8) ? P.av0 : (c < 16) ? P.av1 : (c < 24) ? P.av2 : P.av3;
        float v = 0.f;
        if (av) {
            int hh = c & 7;
#pragma unroll
            for (int d = 0; d < 16; ++d)
                v += P.bias[hh * 16 + d] * av[hh * 16 + d];
        }
        P.bdc[c] = v;
    }
}

// ---------------------------------------------------------------------------
// Kernel B: proj_mfma (+scan1 fused; scan1 needs only count=A, proj needs
// only prep=A — the light scan blocks co-run with the heavy proj blocks).
// h = x @ W + b (fp8 e4m3, [N][128] B) and attn dots (fp32 [N][8]).
// B frags loaded once from global prep buffers; __launch_bounds__(256,2).
// ---------------------------------------------------------------------------
struct PT {
    const float* x; const float* bias; unsigned char* h;
    float* ao0; float* ao1; float* ao2; float* ao3;
    const _Float16* wtg; const _Float16* adtg; const float* bdc;
    int N; int ntiles; int bstart; int nblocks;
};

#define HPAD 136  // halves; row stride 272 B (16B-aligned b128 reads)
#define PROJ_BLKS 1024

__global__ __launch_bounds__(256, 2) void proj_mfma(
    PT t0, PT t1, PT t2,
    const int* __restrict__ cnt, int* __restrict__ part)
{
    __shared__ _Float16 ht[4][16][HPAD];   // 17.4 KB: per-wave h tile (f16)
    __shared__ int swt[4];
    const int tid = threadIdx.x;
    const int lane = tid & 63, wv = tid >> 6;
    const int fi = lane & 15, hi = lane >> 4;

    if (blockIdx.x >= PROJ_BLKS) {
        // scan1: per-1024-chunk totals of cnt
        const int b = blockIdx.x - PROJ_BLKS;
        int i0 = b * 1024 + tid * 4;
        int s = 0;
#pragma unroll
        for (int k = 0; k < 4; ++k) { int i = i0 + k; s += (i < ND) ? cnt[i] : 0; }
#pragma unroll
        for (int off = 1; off < 64; off <<= 1) s += __shfl_xor(s, off);
        if ((tid & 63) == 0) swt[tid >> 6] = s;
        __syncthreads();
        if (tid == 0) part[b] = swt[0] + swt[1] + swt[2] + swt[3];
        return;
    }

    PT A = (blockIdx.x >= t2.bstart) ? t2 : (blockIdx.x >= t1.bstart) ? t1 : t0;

    half8 bfr[8][2], bd[2][2];
#pragma unroll
    for (int nt = 0; nt < 8; ++nt)
#pragma unroll
        for (int kb = 0; kb < 2; ++kb)
            bfr[nt][kb] = *(const half8*)&A.wtg[(nt * 16 + fi) * 64 + kb * 32 + hi * 8];
#pragma unroll
    for (int t = 0; t < 2; ++t)
#pragma unroll
        for (int kb = 0; kb < 2; ++kb)
            bd[t][kb] = *(const half8*)&A.adtg[(t * 16 + fi) * 64 + kb * 32 + hi * 8];

    float bvv[8];
#pragma unroll
    for (int nt = 0; nt < 8; ++nt) bvv[nt] = A.bias[nt * 16 + fi];
    const float bdc0 = A.bdc[fi];
    const float bdc1 = A.bdc[16 + fi];

    float* aolo = (fi >= 8) ? A.ao1 : A.ao0;
    float* aohi = (fi >= 8) ? A.ao3 : A.ao2;
    const bool has_hi = (A.ao2 != nullptr) || (A.ao3 != nullptr);

    const int stride = A.nblocks * 4;
    for (int t = (blockIdx.x - A.bstart) * 4 + wv; t < A.ntiles; t += stride) {
        const int base = t * 16;
        int rsrc = base + fi; if (rsrc >= A.N) rsrc = A.N - 1;
        const float* xp = A.x + (size_t)rsrc * 64 + hi * 8;
        float4 u0 = *(const float4*)(xp);
        float4 u1 = *(const float4*)(xp + 4);
        float4 u2 = *(const float4*)(xp + 32);
        float4 u3 = *(const float4*)(xp + 36);
        half8 a0, a1;
        a0[0] = (_Float16)u0.x; a0[1] = (_Float16)u0.y; a0[2] = (_Float16)u0.z; a0[3] = (_Float16)u0.w;
        a0[4] = (_Float16)u1.x; a0[5] = (_Float16)u1.y; a0[6] = (_Float16)u1.z; a0[7] = (_Float16)u1.w;
        a1[0] = (_Float16)u2.x; a1[1] = (_Float16)u2.y; a1[2] = (_Float16)u2.z; a1[3] = (_Float16)u2.w;
        a1[4] = (_Float16)u3.x; a1[5] = (_Float16)u3.y; a1[6] = (_Float16)u3.z; a1[7] = (_Float16)u3.w;

        float4v c[8];
#pragma unroll
        for (int nt = 0; nt < 8; ++nt) {
            float4v z = {0.f, 0.f, 0.f, 0.f};
            z = __builtin_amdgcn_mfma_f32_16x16x32_f16(a0, bfr[nt][0], z, 0, 0, 0);
            z = __builtin_amdgcn_mfma_f32_16x16x32_f16(a1, bfr[nt][1], z, 0, 0, 0);
            c[nt] = z;
        }
        float4v d0 = {0.f, 0.f, 0.f, 0.f};
        d0 = __builtin_amdgcn_mfma_f32_16x16x32_f16(a0, bd[0][0], d0, 0, 0, 0);
        d0 = __builtin_amdgcn_mfma_f32_16x16x32_f16(a1, bd[0][1], d0, 0, 0, 0);
        float4v d1 = {0.f, 0.f, 0.f, 0.f};
        if (has_hi) {
            d1 = __builtin_amdgcn_mfma_f32_16x16x32_f16(a0, bd[1][0], d1, 0, 0, 0);
            d1 = __builtin_amdgcn_mfma_f32_16x16x32_f16(a1, bd[1][1], d1, 0, 0, 0);
        }

#pragma unroll
        for (int nt = 0; nt < 8; ++nt)
#pragma unroll
            for (int r = 0; r < 4; ++r)
                ht[wv][hi * 4 + r][nt * 16 + fi] = (_Float16)(c[nt][r] + bvv[nt]);
#pragma unroll
        for (int i = 0; i < 4; ++i) {
            int row = i * 4 + hi;
            int node = base + row;
            if (node < A.N) {
                half8 v = *(const half8*)&ht[wv][row][fi * 8];
                int pa = __builtin_amdgcn_cvt_pk_fp8_f32((float)v[0], (float)v[1], 0, false);
                pa = __builtin_amdgcn_cvt_pk_fp8_f32((float)v[2], (float)v[3], pa, true);
                int pb = __builtin_amdgcn_cvt_pk_fp8_f32((float)v[4], (float)v[5], 0, false);
                pb = __builtin_amdgcn_cvt_pk_fp8_f32((float)v[6], (float)v[7], pb, true);
                int2 o = {pa, pb};
                *(int2*)(A.h + (size_t)node * 128 + fi * 8) = o;
            }
        }
        if (aolo) {
#pragma unroll
            for (int r = 0; r < 4; ++r) {
                int node = base + hi * 4 + r;
                if (node < A.N) aolo[(size_t)node * 8 + (fi & 7)] = d0[r] + bdc0;
            }
        }
        if (aohi) {
#pragma unroll
            for (int r = 0; r < 4; ++r) {
                int node = base + hi * 4 + r;
                if (node < A.N) aohi[(size_t)node * 8 + (fi & 7)] = d1[r] + bdc1;
            }
        }
    }
}

// ---------------------------------------------------------------------------
// Kernel C: scan23 — each block replicates the 293-partial exclusive scan
// locally (old scan2), then does scan3's offset/cursor writes.
// ---------------------------------------------------------------------------
__global__ __launch_bounds__(256) void scan23_kernel(
    const int* __restrict__ cnt, const int* __restrict__ part,
    int* __restrict__ off, int* __restrict__ cursor)
{
    __shared__ int sd[256];
    __shared__ int pex[512];
    __shared__ int wt[4];
    const int tid = threadIdx.x, b = blockIdx.x;
    const int lane = tid & 63, wv = tid >> 6;

    int p0 = (2 * tid     < NB) ? part[2 * tid]     : 0;
    int p1 = (2 * tid + 1 < NB) ? part[2 * tid + 1] : 0;
    int ps = p0 + p1;
    sd[tid] = ps; __syncthreads();
    for (int d = 1; d < 256; d <<= 1) {
        int v = (tid >= d) ? sd[tid - d] : 0;
        __syncthreads();
        sd[tid] += v;
        __syncthreads();
    }
    int exc = sd[tid] - ps;
    pex[2 * tid] = exc;
    pex[2 * tid + 1] = exc + p0;
    __syncthreads();

    int i0 = b * 1024 + tid * 4;
    int v[4];
#pragma unroll
    for (int k = 0; k < 4; ++k) { int i = i0 + k; v[k] = (i < ND) ? cnt[i] : 0; }
    int ts = v[0] + v[1] + v[2] + v[3];
    int inc = ts;
#pragma unroll
    for (int d = 1; d < 64; d <<= 1) {
        int u = __shfl_up(inc, d);
        if (lane >= d) inc += u;
    }
    int wexc = inc - ts;
    if (lane == 63) wt[wv] = inc;
    __syncthreads();
    int wbase = 0;
    for (int w = 0; w < wv; ++w) wbase += wt[w];
    int base = pex[b] + wbase + wexc;
    int pre = 0;
#pragma unroll
    for (int k = 0; k < 4; ++k) {
        int i = i0 + k;
        if (i < ND) { off[i] = base + pre; cursor[i] = base + pre; }
        pre += v[k];
    }
}

// ---------------------------------------------------------------------------
// Fill: place src ids in CSR order AND precompute the 8 per-head softmax
// numerators w = exp(leaky_relu(a_s + a_d)) for each edge (f16x8, CSR order).
// ---------------------------------------------------------------------------
__global__ __launch_bounds__(256) void fill_kernel(
    const int* __restrict__ ei00, const int* __restrict__ ei10,
    const int* __restrict__ ei11, const int* __restrict__ ei21,
    const float* __restrict__ as00, const float* __restrict__ ad00,
    const float* __restrict__ as10, const float* __restrict__ ad10,
    const float* __restrict__ as11, const float* __restrict__ ad11,
    const float* __restrict__ as21, const float* __restrict__ ad21,
    int* __restrict__ cursor, int* __restrict__ srcs, _Float16* __restrict__ wgt)
{
    int e = blockIdx.x * 256 + threadIdx.x;
    if (e >= EE) return;
    int src, d, slot;
    const float* asp; const float* adp;
    if (e < E00) {
        src = ei00[e]; d = ei00[E00 + e]; slot = d; asp = as00; adp = ad00;
    } else if (e < E00 + E10) {
        int i = e - E00; src = ei10[i]; d = ei10[E10 + i]; slot = 50000 + d; asp = as10; adp = ad10;
    } else if (e < E00 + E10 + E11) {
        int i = e - E00 - E10; src = ei11[i]; d = ei11[E11 + i]; slot = 100000 + d; asp = as11; adp = ad11;
    } else {
        int i = e - E00 - E10 - E11; src = ei21[i]; d = ei21[E21 + i]; slot = 200000 + d; asp = as21; adp = ad21;
    }
    float4 sa0 = *(const float4*)(asp + (size_t)src * 8);
    float4 sa1 = *(const float4*)(asp + (size_t)src * 8 + 4);
    float4 da0 = *(const float4*)(adp + (size_t)d * 8);
    float4 da1 = *(const float4*)(adp + (size_t)d * 8 + 4);
    float vv[8] = {sa0.x + da0.x, sa0.y + da0.y, sa0.z + da0.z, sa0.w + da0.w,
                   sa1.x + da1.x, sa1.y + da1.y, sa1.z + da1.z, sa1.w + da1.w};
    half8 w;
#pragma unroll
    for (int h = 0; h < 8; ++h) {
        float v = vv[h];
        v = v > 0.f ? v : 0.2f * v;
        w[h] = (_Float16)__expf(v);
    }
    int pos = atomicAdd(&cursor[slot], 1);
    srcs[pos] = src;
    *(half8*)(wgt + (size_t)pos * 8) = w;
}

// ---------------------------------------------------------------------------
// Gather v4: 8 slots per wave, 8 lanes per slot; lane sub covers head sub's
// 16 features (one b128 fp8 load per edge). Weight: wgt[edge*8+sub] (f16).
// 2-edge unroll, predicated; 8 independent slot-chains per wave.
// agg (fp8, relu'ed) written exactly once, b128 per lane.
// ---------------------------------------------------------------------------
__global__ __launch_bounds__(256) void gather_kernel(
    const int* __restrict__ cnt, const int* __restrict__ off,
    const int* __restrict__ srcs, const _Float16* __restrict__ wgt,
    const unsigned char* __restrict__ h0, const unsigned char* __restrict__ h1,
    const unsigned char* __restrict__ h2,
    unsigned char* __restrict__ agg)
{
    const int gid = blockIdx.x * 256 + threadIdx.x;
    const int lane = gid & 63;
    const int g8 = lane >> 3, sub = lane & 7;
    const int slot = (gid >> 6) * 8 + g8;           // grid sized so slot < ND
    const unsigned char* hs = (slot < 50000) ? h0 : (slot < 200000) ? h1 : h2;
    const int deg = cnt[slot], st = off[slot];

    int degm = deg;
    degm = max(degm, __shfl_xor(degm, 8));
    degm = max(degm, __shfl_xor(degm, 16));
    degm = max(degm, __shfl_xor(degm, 32));

    float acc[16];
#pragma unroll
    for (int j = 0; j < 16; ++j) acc[j] = 0.f;
    float sw = 0.f;

    int i = 0;
    for (; i + 2 <= degm; i += 2) {
        bool a0 = (i < deg), a1 = (i + 1 < deg);
        int s0 = 0, s1 = 0;
        if (a0) s0 = srcs[st + i];
        if (a1) s1 = srcs[st + i + 1];
        float w0 = 0.f, w1 = 0.f;
        int4 v0 = {0, 0, 0, 0}, v1 = {0, 0, 0, 0};
        if (a0) { w0 = (float)wgt[(size_t)(st + i) * 8 + sub];
                  v0 = *(const int4*)(hs + (size_t)s0 * 128 + sub * 16); }
        if (a1) { w1 = (float)wgt[(size_t)(st + i + 1) * 8 + sub];
                  v1 = *(const int4*)(hs + (size_t)s1 * 128 + sub * 16); }
        const int wa[4] = {v0.x, v0.y, v0.z, v0.w};
        const int wb[4] = {v1.x, v1.y, v1.z, v1.w};
#pragma unroll
        for (int k = 0; k < 4; ++k) {
            floatx2 fa0 = __builtin_amdgcn_cvt_pk_f32_fp8(wa[k], false);
            floatx2 fa1 = __builtin_amdgcn_cvt_pk_f32_fp8(wa[k], true);
            floatx2 fb0 = __builtin_amdgcn_cvt_pk_f32_fp8(wb[k], false);
            floatx2 fb1 = __builtin_amdgcn_cvt_pk_f32_fp8(wb[k], true);
            acc[4 * k + 0] += w0 * fa0.x + w1 * fb0.x;
            acc[4 * k + 1] += w0 * fa0.y + w1 * fb0.y;
            acc[4 * k + 2] += w0 * fa1.x + w1 * fb1.x;
            acc[4 * k + 3] += w0 * fa1.y + w1 * fb1.y;
        }
        sw += w0 + w1;
    }
    if (i < degm) {
        bool a0 = (i < deg);
        int s0 = 0;
        if (a0) s0 = srcs[st + i];
        float w0 = 0.f;
        int4 v0 = {0, 0, 0, 0};
        if (a0) { w0 = (float)wgt[(size_t)(st + i) * 8 + sub];
                  v0 = *(const int4*)(hs + (size_t)s0 * 128 + sub * 16); }
        const int wa[4] = {v0.x, v0.y, v0.z, v0.w};
#pragma unroll
        for (int k = 0; k < 4; ++k) {
            floatx2 fa0 = __builtin_amdgcn_cvt_pk_f32_fp8(wa[k], false);
            floatx2 fa1 = __builtin_amdgcn_cvt_pk_f32_fp8(wa[k], true);
            acc[4 * k + 0] += w0 * fa0.x;
            acc[4 * k + 1] += w0 * fa0.y;
            acc[4 * k + 2] += w0 * fa1.x;
            acc[4 * k + 3] += w0 * fa1.y;
        }
        sw += w0;
    }

    float rr = __builtin_amdgcn_rcpf(sw + 1e-16f);
    int4 o;
    int pk[4];
#pragma unroll
    for (int k = 0; k < 4; ++k) {
        float r0 = fmaxf(acc[4 * k + 0] * rr, 0.f);
        float r1 = fmaxf(acc[4 * k + 1] * rr, 0.f);
        float r2 = fmaxf(acc[4 * k + 2] * rr, 0.f);
        float r3 = fmaxf(acc[4 * k + 3] * rr, 0.f);
        int p = __builtin_amdgcn_cvt_pk_fp8_f32(r0, r1, 0, false);
        p = __builtin_amdgcn_cvt_pk_fp8_f32(r2, r3, p, true);
        pk[k] = p;
    }
    o.x = pk[0]; o.y = pk[1]; o.z = pk[2]; o.w = pk[3];
    *(int4*)(agg + (size_t)slot * 128 + sub * 16) = o;
}

// ---------------------------------------------------------------------------
// Semantic (fp8 MFMA over all 4 metapaths) + fused final epilogue (last
// block through a device atomic counter computes softmax+classifier+sigmoid).
// B frags loaded once from global kwf8. metapath: 3=t>=12500, 2=t>=6250,
// 1=t>=3125, else 0 (u00,b10,u11,b21).
// ---------------------------------------------------------------------------
__global__ __launch_bounds__(256, 2) void semantic_kernel(
    const unsigned char* __restrict__ agg, const unsigned char* __restrict__ kwf8,
    const float* __restrict__ kb, const float* __restrict__ q,
    const float* __restrict__ lb,
    float* __restrict__ cs2, float* __restrict__ score,
    unsigned int* __restrict__ done, float* __restrict__ out)
{
    __shared__ float redv[12];
    const int tid = threadIdx.x;
    const int lane = tid & 63, wv = tid >> 6;
    const int fi = lane & 15, hi = lane >> 4;

    if (tid < 12) redv[tid] = 0.f;
    __syncthreads();

    long bf[9][4];
#pragma unroll
    for (int ft = 0; ft < 9; ++ft)
#pragma unroll
        for (int kk = 0; kk < 4; ++kk)
            bf[ft][kk] = *(const long*)&kwf8[(ft * 16 + fi) * 128 + kk * 32 + hi * 8];

    float qv[8], kbv[8];
#pragma unroll
    for (int ft = 0; ft < 8; ++ft) {
        qv[ft] = q[ft * 16 + fi];
        kbv[ft] = kb[ft * 16 + fi];
    }

    float sc[4] = {0.f, 0.f, 0.f, 0.f};
    float cs[4] = {0.f, 0.f, 0.f, 0.f};
    const int wid = blockIdx.x * 4 + wv;
    const int nw = gridDim.x * 4;

    long af[4] = {0, 0, 0, 0};
    int t = wid;
    if (t < NT_ALL) {
        const unsigned char* rowp = agg + ((size_t)(t * 16 + fi) * 128 + hi * 8);
        af[0] = *(const long*)(rowp);
        af[1] = *(const long*)(rowp + 32);
        af[2] = *(const long*)(rowp + 64);
        af[3] = *(const long*)(rowp + 96);
    }
    while (t < NT_ALL) {
        const int tn = t + nw;
        long afn[4] = {0, 0, 0, 0};
        if (tn < NT_ALL) {
            const unsigned char* rowp = agg + ((size_t)(tn * 16 + fi) * 128 + hi * 8);
            afn[0] = *(const long*)(rowp);
            afn[1] = *(const long*)(rowp + 32);
            afn[2] = *(const long*)(rowp + 64);
            afn[3] = *(const long*)(rowp + 96);
        }
        const int m = (t >= 12500) ? 3 : (t >= 6250) ? 2 : (t >= 3125) ? 1 : 0;
        float tsc = 0.f, tcs;
#pragma unroll
        for (int ft = 0; ft < 8; ++ft) {
            float4v c = {0.f, 0.f, 0.f, 0.f};
            c = __builtin_amdgcn_mfma_f32_16x16x32_fp8_fp8(af[0], bf[ft][0], c, 0, 0, 0);
            c = __builtin_amdgcn_mfma_f32_16x16x32_fp8_fp8(af[1], bf[ft][1], c, 0, 0, 0);
            c = __builtin_amdgcn_mfma_f32_16x16x32_fp8_fp8(af[2], bf[ft][2], c, 0, 0, 0);
            c = __builtin_amdgcn_mfma_f32_16x16x32_fp8_fp8(af[3], bf[ft][3], c, 0, 0, 0);
#pragma unroll
            for (int r = 0; r < 4; ++r) {
                float y = c[r] + kbv[ft];
                float e = __expf(2.f * y);
                tsc += qv[ft] * (1.f - 2.f * __builtin_amdgcn_rcpf(e + 1.f));
            }
        }
        {
            float4v c = {0.f, 0.f, 0.f, 0.f};
            c = __builtin_amdgcn_mfma_f32_16x16x32_fp8_fp8(af[0], bf[8][0], c, 0, 0, 0);
            c = __builtin_amdgcn_mfma_f32_16x16x32_fp8_fp8(af[1], bf[8][1], c, 0, 0, 0);
            c = __builtin_amdgcn_mfma_f32_16x16x32_fp8_fp8(af[2], bf[8][2], c, 0, 0, 0);
            c = __builtin_amdgcn_mfma_f32_16x16x32_fp8_fp8(af[3], bf[8][3], c, 0, 0, 0);
            tcs = c[0] + c[1] + c[2] + c[3];
        }
        if (m == 0)      { sc[0] += tsc; cs[0] += tcs; }
        else if (m == 1) { sc[1] += tsc; cs[1] += tcs; }
        else if (m == 2) { sc[2] += tsc; cs[2] += tcs; }
        else             { sc[3] += tsc; cs[3] += tcs; }
        t = tn;
        af[0] = afn[0]; af[1] = afn[1]; af[2] = afn[2]; af[3] = afn[3];
    }

#pragma unroll
    for (int m = 0; m < 4; ++m) {
        float s = sc[m];
#pragma unroll
        for (int off = 1; off < 64; off <<= 1) s += __shfl_xor(s, off);
        if (lane == 0 && s != 0.f) atomicAdd(&redv[m], s);
        float v = cs[m];
        v += __shfl_xor(v, 16);
        v += __shfl_xor(v, 32);
        if (hi == 0 && fi < 2 && v != 0.f) atomicAdd(&redv[4 + 2 * m + fi], v);
    }
    __syncthreads();
    if (tid < 4)              atomicAdd(&score[tid], redv[tid]);
    if (tid >= 4 && tid < 12) atomicAdd(&cs2[tid - 4], redv[tid]);

    // last-block final epilogue
    __syncthreads();
    if (tid == 0) {
        __threadfence();
        unsigned int old = atomicAdd(done, 1u);
        if (old == gridDim.x - 1) {
            __threadfence();
            float s0 = score[0] / (float)N0;
            float s1 = score[1] / (float)N0;
            float s2 = score[2] / (float)N1;
            float s3 = score[3] / (float)N1;
            float m0 = fmaxf(s0, s1);
            float e0 = __expf(s0 - m0), e1 = __expf(s1 - m0);
            float a0 = e0 / (e0 + e1), a1 = e1 / (e0 + e1);
            float m1 = fmaxf(s2, s3);
            float e2 = __expf(s2 - m1), e3 = __expf(s3 - m1);
            float a2 = e2 / (e2 + e3), a3 = e3 / (e2 + e3);
            float z0 = a0 * cs2[0] + a1 * cs2[2] + a2 * cs2[4] + a3 * cs2[6] + lb[0];
            float z1 = a0 * cs2[1] + a1 * cs2[3] + a2 * cs2[5] + a3 * cs2[7] + lb[1];
            out[0] = 1.f / (1.f + __expf(-z0));
            out[1] = 1.f / (1.f + __expf(-z1));
        }
    }
}

extern "C" void kernel_launch(void* const* d_in, const int* in_sizes, int n_in,
                              void* d_out, int out_size, void* d_ws, size_t ws_size,
                              hipStream_t stream)
{
    const float* x0  = (const float*)d_in[0];
    const float* x1  = (const float*)d_in[1];
    const float* x2  = (const float*)d_in[2];
    const int* ei00  = (const int*)d_in[3];
    const int* ei11  = (const int*)d_in[4];
    const int* ei10  = (const int*)d_in[5];
    const int* ei21  = (const int*)d_in[6];
    const float* W0  = (const float*)d_in[7];  const float* b0 = (const float*)d_in[8];
    const float* W1  = (const float*)d_in[9];  const float* b1 = (const float*)d_in[10];
    const float* W2  = (const float*)d_in[11]; const float* b2 = (const float*)d_in[12];
    const float* as00 = (const float*)d_in[13]; const float* ad00 = (const float*)d_in[14];
    const float* as11 = (const float*)d_in[15]; const float* ad11 = (const float*)d_in[16];
    const float* as10 = (const float*)d_in[17]; const float* ad10 = (const float*)d_in[18];
    const float* as21 = (const float*)d_in[19]; const float* ad21 = (const float*)d_in[20];
    const float* kw  = (const float*)d_in[21]; const float* kb  = (const float*)d_in[22];
    const float* q   = (const float*)d_in[23];
    const float* lw  = (const float*)d_in[24]; const float* lb  = (const float*)d_in[25];
    float* out = (float*)d_out;

    char* p = (char*)d_ws;
    auto alloc = [&](size_t bytes) {
        char* r = p;
        p += (bytes + 255) & ~(size_t)255;
        return r;
    };
    unsigned char* h0 = (unsigned char*)alloc((size_t)N0 * 128);   // fp8 [N][128]
    unsigned char* h1 = (unsigned char*)alloc((size_t)N1 * 128);
    unsigned char* h2 = (unsigned char*)alloc((size_t)N2 * 128);
    float* o_as00 = (float*)alloc((size_t)N0 * 32);
    float* o_ad00 = (float*)alloc((size_t)N0 * 32);
    float* o_as11 = (float*)alloc((size_t)N1 * 32);
    float* o_ad11 = (float*)alloc((size_t)N1 * 32);
    float* o_as10 = (float*)alloc((size_t)N1 * 32);   // src of b10 = cell1
    float* o_ad10 = (float*)alloc((size_t)N0 * 32);   // dst of b10 = cell0
    float* o_as21 = (float*)alloc((size_t)N2 * 32);   // src of b21 = cell2
    float* o_ad21 = (float*)alloc((size_t)N1 * 32);   // dst of b21 = cell1
    int* off    = (int*)alloc((size_t)ND * 4);
    int* cursor = (int*)alloc((size_t)ND * 4);
    int* part   = (int*)alloc((size_t)512 * 4);
    int* srcs   = (int*)alloc((size_t)EE * 4);
    _Float16* wgt = (_Float16*)alloc((size_t)EE * 16);             // f16x8 per edge
    unsigned char* agg = (unsigned char*)alloc((size_t)ND * 128);  // fp8 [u00|b10|u11|b21]
    _Float16* wtg0 = (_Float16*)alloc(128 * 64 * 2);
    _Float16* wtg1 = (_Float16*)alloc(128 * 64 * 2);
    _Float16* wtg2 = (_Float16*)alloc(128 * 64 * 2);
    _Float16* adtg0 = (_Float16*)alloc(32 * 64 * 2);
    _Float16* adtg1 = (_Float16*)alloc(32 * 64 * 2);
    _Float16* adtg2 = (_Float16*)alloc(32 * 64 * 2);
    float* bdcg = (float*)alloc(3 * 32 * 4);
    unsigned char* kwf8 = (unsigned char*)alloc(144 * 128);
    // ---- zero region (contiguous) ----
    char* zstart = p;
    int* cnt = (int*)alloc((size_t)ND * 4);
    float* colsum2 = (float*)alloc(8 * 4);
    float* score   = (float*)alloc(4 * 4);
    unsigned int* done = (unsigned int*)alloc(4);
    size_t zbytes = (size_t)(p - zstart);

    (void)hipMemsetAsync(zstart, 0, zbytes, stream);

    // A: prep (+ count)
    PrepT pp0 = {W0, b0, as00, ad00, ad10, nullptr, wtg0, adtg0, bdcg + 0};
    PrepT pp1 = {W1, b1, as11, ad11, as10, ad21,    wtg1, adtg1, bdcg + 32};
    PrepT pp2 = {W2, b2, as21, nullptr, nullptr, nullptr, wtg2, adtg2, bdcg + 64};
    prep_kernel<<<32 + (EE + 255) / 256, 256, 0, stream>>>(
        pp0, pp1, pp2, kw, lw, kwf8, ei00, ei10, ei11, ei21, cnt);

    // B: proj (+ scan1). proj blocks [0,296) cell0, [296,880) cell1, [880,1024) cell2
    PT t0 = {x0, b0, h0,
             o_as00, o_ad00, o_ad10, nullptr,
             wtg0, adtg0, bdcg + 0,
             N0, 3125, 0, 296};
    PT t1 = {x1, b1, h1,
             o_as11, o_ad11, o_as10, o_ad21,
             wtg1, adtg1, bdcg + 32,
             N1, 6250, 296, 584};
    PT t2 = {x2, b2, h2,
             o_as21, nullptr, nullptr, nullptr,
             wtg2, adtg2, bdcg + 64,
             N2, 1563, 880, 144};
    proj_mfma<<<PROJ_BLKS + NB, 256, 0, stream>>>(t0, t1, t2, cnt, part);

    // C: scan2+scan3 fused
    scan23_kernel<<<NB, 256, 0, stream>>>(cnt, part, off, cursor);

    // D: fill (CSR placement + per-edge softmax numerators)
    fill_kernel<<<(EE + 255) / 256, 256, 0, stream>>>(ei00, ei10, ei11, ei21,
        o_as00, o_ad00, o_as10, o_ad10, o_as11, o_ad11, o_as21, o_ad21,
        cursor, srcs, wgt);

    // E: gather v4 (8 slots/wave)
    gather_kernel<<<ND / 32, 256, 0, stream>>>(cnt, off, srcs, wgt, h0, h1, h2, agg);

    // F: semantic (+ fused final epilogue)
    semantic_kernel<<<1024, 256, 0, stream>>>(agg, kwf8, kb, q, lb,
                                              colsum2, score, done, out);
}